// Round 1
// baseline (563.416 us; speedup 1.0000x reference)
//
#include <hip/hip_runtime.h>
#include <hip/hip_bf16.h>

#define DI __device__ __forceinline__

namespace {
constexpr int N_ = 128, S_ = 32, P_ = 16, F_ = 256, H_ = 4, NH_ = 128;
constexpr int SP_ = S_ * P_;          // 512
constexpr int ROWS_ = N_ * SP_;       // 65536
constexpr int GC_ = H_ * NH_;         // 512
constexpr float SLOPE_ = 0.2f;
constexpr int OUT_ELEMS = N_ * SP_ * NH_;    // 8,388,608
}

DI float lrelu(float x) { return x >= 0.f ? x : SLOPE_ * x; }

DI unsigned short f2bf(float x) {
    unsigned int u = __float_as_uint(x);
    u += 0x7fffu + ((u >> 16) & 1u);
    return (unsigned short)(u >> 16);
}
DI float bf2f(unsigned short b) { return __uint_as_float(((unsigned int)b) << 16); }

// ---------------------------------------------------------------------------
// prep: wl_s[f][h] = sum_nh W_l[f][h*128+nh]*aw[nh];  wr_s likewise with aw[128+]
// 2048 threads total
__global__ __launch_bounds__(256) void prep_kernel(
    const float* __restrict__ Wl, const float* __restrict__ Wr,
    const float* __restrict__ aw, float* __restrict__ wls, float* __restrict__ wrs) {
    int t = blockIdx.x * 256 + threadIdx.x;   // 0..2047
    int which = t >> 10;                       // 0 -> wl, 1 -> wr
    int f = (t & 1023) >> 2;
    int h = t & 3;
    const float* W = which ? Wr : Wl;
    const float* a = aw + which * NH_;
    const float* wrow = W + (size_t)f * GC_ + h * NH_;
    float s = 0.f;
    for (int k = 0; k < NH_; ++k) s += wrow[k] * a[k];
    (which ? wrs : wls)[f * H_ + h] = s;
}

// ---------------------------------------------------------------------------
// scores: one thread per row r = n*512 + sp of h.  sl/sr layout: [sp][n][h]
__global__ __launch_bounds__(256) void score_kernel(
    const float* __restrict__ hm, const float* __restrict__ wls,
    const float* __restrict__ wrs, float* __restrict__ sl, float* __restrict__ sr) {
    int r = blockIdx.x * 256 + threadIdx.x;    // 0..65535
    const float4* hr  = (const float4*)(hm + (size_t)r * F_);
    const float4* wl4 = (const float4*)wls;    // [f] -> 4 heads
    const float4* wr4 = (const float4*)wrs;
    float4 al = {0.f,0.f,0.f,0.f}, ar = {0.f,0.f,0.f,0.f};
    for (int f0 = 0; f0 < F_; f0 += 4) {
        float4 hv = hr[f0 >> 2];
        float hx[4] = {hv.x, hv.y, hv.z, hv.w};
#pragma unroll
        for (int u = 0; u < 4; ++u) {
            float4 wl = wl4[f0 + u], wr = wr4[f0 + u];
            al.x += hx[u] * wl.x; al.y += hx[u] * wl.y;
            al.z += hx[u] * wl.z; al.w += hx[u] * wl.w;
            ar.x += hx[u] * wr.x; ar.y += hx[u] * wr.y;
            ar.z += hx[u] * wr.z; ar.w += hx[u] * wr.w;
        }
    }
    int n = r >> 9, sp = r & 511;
    ((float4*)sl)[sp * N_ + n] = al;
    ((float4*)sr)[sp * N_ + n] = ar;
}

// ---------------------------------------------------------------------------
// g_r GEMM: (65536 x 256) @ (256 x 512) fp32, output bf16 in [sp][n][col] layout
__global__ __launch_bounds__(256) void gemm_gr(
    const float* __restrict__ hm, const float* __restrict__ Wr,
    unsigned short* __restrict__ g) {
    constexpr int BM = 128, BN = 128, BK = 32;
    __shared__ float Ah[BK][BM];        // [kk][m]
    __shared__ float Bh[BK][132];       // [kk][c], padded

    int cb = blockIdx.x & 3, rb = blockIdx.x >> 2;
    int t = threadIdx.x;
    int wave = t >> 6, lane = t & 63;
    int tr = lane >> 3, tc = lane & 7;
    int wr = wave >> 1, wc = wave & 1;
    int r0 = wr * 64 + tr * 8;
    int c0 = wc * 64 + tc * 8;

    int lm  = t >> 1;                 // A stage: row
    int kk0 = (t & 1) * 16;           // A stage: k half
    int bkk = t >> 3;                 // B stage: k row
    int bc0 = (t & 7) * 16;           // B stage: col base

    const float* arow = hm + (size_t)(rb * BM + lm) * F_;
    float acc[8][8] = {};

    for (int k0 = 0; k0 < F_; k0 += BK) {
#pragma unroll
        for (int u = 0; u < 4; ++u) {
            float4 v = *(const float4*)(arow + k0 + kk0 + u * 4);
            Ah[kk0 + u*4 + 0][lm] = v.x;
            Ah[kk0 + u*4 + 1][lm] = v.y;
            Ah[kk0 + u*4 + 2][lm] = v.z;
            Ah[kk0 + u*4 + 3][lm] = v.w;
        }
#pragma unroll
        for (int u = 0; u < 4; ++u) {
            float4 v = *(const float4*)(Wr + (size_t)(k0 + bkk) * GC_ + cb * BN + bc0 + u * 4);
            *(float4*)&Bh[bkk][bc0 + u * 4] = v;
        }
        __syncthreads();
#pragma unroll
        for (int kk = 0; kk < BK; ++kk) {
            float a[8], b[8];
            *(float4*)&a[0] = *(float4*)&Ah[kk][r0];
            *(float4*)&a[4] = *(float4*)&Ah[kk][r0 + 4];
            *(float4*)&b[0] = *(float4*)&Bh[kk][c0];
            *(float4*)&b[4] = *(float4*)&Bh[kk][c0 + 4];
#pragma unroll
            for (int i = 0; i < 8; ++i)
#pragma unroll
                for (int j = 0; j < 8; ++j) acc[i][j] += a[i] * b[j];
        }
        __syncthreads();
    }

    // epilogue: row r = rb*128 + lmr ; n = r/512, sp = r%512 (n constant per block)
    int rbase = rb * BM;
    int n   = rbase >> 9;
    int spb = rbase & 511;
#pragma unroll
    for (int i = 0; i < 8; ++i) {
        int sp = spb + r0 + i;
        union { unsigned short us[8]; uint4 v; } pk;
#pragma unroll
        for (int j = 0; j < 8; ++j) pk.us[j] = f2bf(acc[i][j]);
        size_t off = (size_t)sp * 65536 + (size_t)n * 512 + cb * BN + c0;
        *(uint4*)(g + off) = pk.v;
    }
}

// ---------------------------------------------------------------------------
// softmax: one block per sp.  Writes a[sp][i][j][h] (float4 over h) to d_out.
__global__ __launch_bounds__(256) void softmax_kernel(
    const float* __restrict__ sl_g, const float* __restrict__ sr_g,
    float* __restrict__ a_out) {
    __shared__ float4 sl[N_], sr[N_], mrow[N_], invs[N_];
    __shared__ float mx1[H_], mx2[H_];
    __shared__ int   id1[H_];

    int sp = blockIdx.x;
    int t = threadIdx.x;
    if (t < 128)       sl[t]       = ((const float4*)sl_g)[sp * N_ + t];
    else               sr[t - 128] = ((const float4*)sr_g)[sp * N_ + (t - 128)];
    __syncthreads();

    if (t < H_) {
        float m1 = -1e30f; int i1 = 0;
        for (int j = 0; j < N_; ++j) {
            float v = ((const float*)&sl[j])[t];
            if (v > m1) { m1 = v; i1 = j; }
        }
        float m2 = -1e30f;
        for (int j = 0; j < N_; ++j)
            if (j != i1) m2 = fmaxf(m2, ((const float*)&sl[j])[t]);
        mx1[t] = m1; mx2[t] = m2; id1[t] = i1;
    }
    __syncthreads();

    {   // pass 1: per-(i,h) max (via monotonicity) and sum
        int i = t & 127, h0 = t >> 7;       // handles heads h0 and h0+2
        int ha = h0, hb = h0 + 2;
        float sra = ((const float*)&sr[i])[ha];
        float srb = ((const float*)&sr[i])[hb];
        float ma = lrelu(sra + ((id1[ha] == i) ? mx2[ha] : mx1[ha]));
        float mb = lrelu(srb + ((id1[hb] == i) ? mx2[hb] : mx1[hb]));
        float suma = 0.f, sumb = 0.f;
        for (int j = 0; j < N_; ++j) {
            float4 slj = sl[j];
            float ea = lrelu(sra + ((const float*)&slj)[ha]);
            float eb = lrelu(srb + ((const float*)&slj)[hb]);
            float pa = __expf(ea - ma);
            float pb = __expf(eb - mb);
            if (j != i) { suma += pa; sumb += pb; }
        }
        ((float*)&mrow[i])[ha] = ma;  ((float*)&mrow[i])[hb] = mb;
        ((float*)&invs[i])[ha] = 1.f / suma; ((float*)&invs[i])[hb] = 1.f / sumb;
    }
    __syncthreads();

    // pass 2: write normalized a (float4 over 4 heads, coalesced)
    float4* a_base = (float4*)(a_out + (size_t)sp * (N_ * N_ * H_));
    int jdx = t & 127, half = t >> 7;
    for (int it = 0; it < 64; ++it) {
        int i = it * 2 + half;
        float4 srv = sr[i], m4 = mrow[i], s4 = invs[i], slv = sl[jdx];
        float4 p;
        p.x = __expf(lrelu(srv.x + slv.x) - m4.x) * s4.x;
        p.y = __expf(lrelu(srv.y + slv.y) - m4.y) * s4.y;
        p.z = __expf(lrelu(srv.z + slv.z) - m4.z) * s4.z;
        p.w = __expf(lrelu(srv.w + slv.w) - m4.w) * s4.w;
        if (jdx == i) { p.x = 0.f; p.y = 0.f; p.z = 0.f; p.w = 0.f; }
        a_base[i * N_ + jdx] = p;
    }
}

// ---------------------------------------------------------------------------
// PV: one block per sp; loop heads; out[i][f] = 0.25 * sum_h sum_j a[i][j][h]*g[j][h*128+f]
__global__ __launch_bounds__(256) void pv_kernel(
    const float* __restrict__ a_g, const unsigned short* __restrict__ g,
    float* __restrict__ out) {
    __shared__ float A2T[128][132];    // [j][i]
    __shared__ float G2[128][132];     // [j][f]

    int sp = blockIdx.x;
    int t = threadIdx.x;
    int wave = t >> 6, lane = t & 63;
    int tr = lane >> 3, tc = lane & 7;
    int wr = wave >> 1, wc = wave & 1;
    int r0 = wr * 64 + tr * 8, c0 = wc * 64 + tc * 8;

    const float* a_base = a_g + (size_t)sp * (N_ * N_ * H_);
    const unsigned short* g_base = g + (size_t)sp * 65536;
    float acc[8][8] = {};

    for (int h = 0; h < H_; ++h) {
        for (int k = 0; k < 64; ++k) {
            int idx = t + k * 256;          // 0..16383
            int i = idx >> 7, j = idx & 127;
            A2T[j][i] = a_base[(size_t)(i * 128 + j) * 4 + h];
        }
        for (int k = 0; k < 8; ++k) {
            int idx8 = t + k * 256;         // 0..2047, 8 floats each
            int j = idx8 >> 4, f0 = (idx8 & 15) * 8;
            uint4 raw = *(const uint4*)(g_base + (size_t)j * 512 + h * 128 + f0);
            const unsigned short* bp = (const unsigned short*)&raw;
#pragma unroll
            for (int u = 0; u < 8; ++u) G2[j][f0 + u] = bf2f(bp[u]);
        }
        __syncthreads();
        for (int j = 0; j < 128; ++j) {
            float av[8], gv[8];
            *(float4*)&av[0] = *(float4*)&A2T[j][r0];
            *(float4*)&av[4] = *(float4*)&A2T[j][r0 + 4];
            *(float4*)&gv[0] = *(float4*)&G2[j][c0];
            *(float4*)&gv[4] = *(float4*)&G2[j][c0 + 4];
#pragma unroll
            for (int i = 0; i < 8; ++i)
#pragma unroll
                for (int jj = 0; jj < 8; ++jj) acc[i][jj] += av[i] * gv[jj];
        }
        __syncthreads();
    }

#pragma unroll
    for (int i = 0; i < 8; ++i) {
        int n = r0 + i;
        float4 v0 = {acc[i][0]*0.25f, acc[i][1]*0.25f, acc[i][2]*0.25f, acc[i][3]*0.25f};
        float4 v1 = {acc[i][4]*0.25f, acc[i][5]*0.25f, acc[i][6]*0.25f, acc[i][7]*0.25f};
        float* op = out + (size_t)n * 65536 + (size_t)sp * 128 + c0;
        *(float4*)op       = v0;
        *(float4*)(op + 4) = v1;
    }
}

// ---------------------------------------------------------------------------
extern "C" void kernel_launch(void* const* d_in, const int* in_sizes, int n_in,
                              void* d_out, int out_size, void* d_ws, size_t ws_size,
                              hipStream_t stream) {
    const float* hm = (const float*)d_in[0];
    const float* Wl = (const float*)d_in[1];
    const float* Wr = (const float*)d_in[2];
    const float* aw = (const float*)d_in[3];

    float* out   = (float*)d_out;
    float* a_out = out + OUT_ELEMS;

    char* ws = (char*)d_ws;
    unsigned short* g = (unsigned short*)ws;              // 33,554,432 bf16 = 64 MiB
    float* sl  = (float*)(ws + (size_t)67108864);         // 512*128*4 f32 = 1 MiB
    float* sr  = sl + SP_ * N_ * H_;                      // 1 MiB
    float* wls = sr + SP_ * N_ * H_;                      // 4 KiB
    float* wrs = wls + F_ * H_;                           // 4 KiB

    prep_kernel  <<<8,          256, 0, stream>>>(Wl, Wr, aw, wls, wrs);
    score_kernel <<<ROWS_ / 256,256, 0, stream>>>(hm, wls, wrs, sl, sr);
    gemm_gr      <<<2048,       256, 0, stream>>>(hm, Wr, g);
    softmax_kernel<<<SP_,       256, 0, stream>>>(sl, sr, a_out);
    pv_kernel    <<<SP_,        256, 0, stream>>>(a_out, g, out);
}

// Round 2
// 371.834 us; speedup vs baseline: 1.5152x; 1.5152x over previous
//
#include <hip/hip_runtime.h>
#include <hip/hip_bf16.h>

#define DI __device__ __forceinline__

namespace {
constexpr int N_ = 128, S_ = 32, P_ = 16, F_ = 256, H_ = 4, NH_ = 128;
constexpr int SP_ = S_ * P_;          // 512
constexpr int ROWS_ = N_ * SP_;       // 65536
constexpr int GC_ = H_ * NH_;         // 512
constexpr float SLOPE_ = 0.2f;
constexpr int OUT_ELEMS = N_ * SP_ * NH_;    // 8,388,608
}

DI float lrelu(float x) { return x >= 0.f ? x : SLOPE_ * x; }

DI unsigned short f2bf(float x) {
    unsigned int u = __float_as_uint(x);
    u += 0x7fffu + ((u >> 16) & 1u);
    return (unsigned short)(u >> 16);
}
DI float bf2f(unsigned short b) { return __uint_as_float(((unsigned int)b) << 16); }

typedef __bf16 bf16x8 __attribute__((ext_vector_type(8)));
typedef float  f32x4  __attribute__((ext_vector_type(4)));

DI f32x4 mfma16(uint4 a, uint4 b, f32x4 c) {
    return __builtin_amdgcn_mfma_f32_16x16x32_bf16(
        __builtin_bit_cast(bf16x8, a), __builtin_bit_cast(bf16x8, b), c, 0, 0, 0);
}

// ---------------------------------------------------------------------------
// prep: wl_s[f][h] = sum_nh W_l[f][h*128+nh]*aw[nh];  wr_s likewise with aw[128+]
__global__ __launch_bounds__(256) void prep_kernel(
    const float* __restrict__ Wl, const float* __restrict__ Wr,
    const float* __restrict__ aw, float* __restrict__ wls, float* __restrict__ wrs) {
    int t = blockIdx.x * 256 + threadIdx.x;   // 0..2047
    int which = t >> 10;                       // 0 -> wl, 1 -> wr
    int f = (t & 1023) >> 2;
    int h = t & 3;
    const float* W = which ? Wr : Wl;
    const float* a = aw + which * NH_;
    const float* wrow = W + (size_t)f * GC_ + h * NH_;
    float s = 0.f;
    for (int k = 0; k < NH_; ++k) s += wrow[k] * a[k];
    (which ? wrs : wls)[f * H_ + h] = s;
}

// ---------------------------------------------------------------------------
// scores: one thread per row r = n*512 + sp of h.  sl/sr layout: [sp][n][h]
__global__ __launch_bounds__(256) void score_kernel(
    const float* __restrict__ hm, const float* __restrict__ wls,
    const float* __restrict__ wrs, float* __restrict__ sl, float* __restrict__ sr) {
    int r = blockIdx.x * 256 + threadIdx.x;    // 0..65535
    const float4* hr  = (const float4*)(hm + (size_t)r * F_);
    const float4* wl4 = (const float4*)wls;    // [f] -> 4 heads
    const float4* wr4 = (const float4*)wrs;
    float4 al = {0.f,0.f,0.f,0.f}, ar = {0.f,0.f,0.f,0.f};
    for (int f0 = 0; f0 < F_; f0 += 4) {
        float4 hv = hr[f0 >> 2];
        float hx[4] = {hv.x, hv.y, hv.z, hv.w};
#pragma unroll
        for (int u = 0; u < 4; ++u) {
            float4 wl = wl4[f0 + u], wr = wr4[f0 + u];
            al.x += hx[u] * wl.x; al.y += hx[u] * wl.y;
            al.z += hx[u] * wl.z; al.w += hx[u] * wl.w;
            ar.x += hx[u] * wr.x; ar.y += hx[u] * wr.y;
            ar.z += hx[u] * wr.z; ar.w += hx[u] * wr.w;
        }
    }
    int n = r >> 9, sp = r & 511;
    ((float4*)sl)[sp * N_ + n] = al;
    ((float4*)sr)[sp * N_ + n] = ar;
}

// ---------------------------------------------------------------------------
// g_r GEMM: (65536 x 256) @ (256 x 512) fp32, output bf16 in [sp][n][col] layout
__global__ __launch_bounds__(256) void gemm_gr(
    const float* __restrict__ hm, const float* __restrict__ Wr,
    unsigned short* __restrict__ g) {
    constexpr int BM = 128, BN = 128, BK = 32;
    __shared__ float Ah[BK][BM];        // [kk][m]
    __shared__ float Bh[BK][132];       // [kk][c], padded

    int cb = blockIdx.x & 3, rb = blockIdx.x >> 2;
    int t = threadIdx.x;
    int wave = t >> 6, lane = t & 63;
    int tr = lane >> 3, tc = lane & 7;
    int wr = wave >> 1, wc = wave & 1;
    int r0 = wr * 64 + tr * 8;
    int c0 = wc * 64 + tc * 8;

    int lm  = t >> 1;                 // A stage: row
    int kk0 = (t & 1) * 16;           // A stage: k half
    int bkk = t >> 3;                 // B stage: k row
    int bc0 = (t & 7) * 16;           // B stage: col base

    const float* arow = hm + (size_t)(rb * BM + lm) * F_;
    float acc[8][8] = {};

    for (int k0 = 0; k0 < F_; k0 += BK) {
#pragma unroll
        for (int u = 0; u < 4; ++u) {
            float4 v = *(const float4*)(arow + k0 + kk0 + u * 4);
            Ah[kk0 + u*4 + 0][lm] = v.x;
            Ah[kk0 + u*4 + 1][lm] = v.y;
            Ah[kk0 + u*4 + 2][lm] = v.z;
            Ah[kk0 + u*4 + 3][lm] = v.w;
        }
#pragma unroll
        for (int u = 0; u < 4; ++u) {
            float4 v = *(const float4*)(Wr + (size_t)(k0 + bkk) * GC_ + cb * BN + bc0 + u * 4);
            *(float4*)&Bh[bkk][bc0 + u * 4] = v;
        }
        __syncthreads();
#pragma unroll
        for (int kk = 0; kk < BK; ++kk) {
            float a[8], b[8];
            *(float4*)&a[0] = *(float4*)&Ah[kk][r0];
            *(float4*)&a[4] = *(float4*)&Ah[kk][r0 + 4];
            *(float4*)&b[0] = *(float4*)&Bh[kk][c0];
            *(float4*)&b[4] = *(float4*)&Bh[kk][c0 + 4];
#pragma unroll
            for (int i = 0; i < 8; ++i)
#pragma unroll
                for (int j = 0; j < 8; ++j) acc[i][j] += a[i] * b[j];
        }
        __syncthreads();
    }

    int rbase = rb * BM;
    int n   = rbase >> 9;
    int spb = rbase & 511;
#pragma unroll
    for (int i = 0; i < 8; ++i) {
        int sp = spb + r0 + i;
        union { unsigned short us[8]; uint4 v; } pk;
#pragma unroll
        for (int j = 0; j < 8; ++j) pk.us[j] = f2bf(acc[i][j]);
        size_t off = (size_t)sp * 65536 + (size_t)n * 512 + cb * BN + c0;
        *(uint4*)(g + off) = pk.v;
    }
}

// ---------------------------------------------------------------------------
// softmax: one block per sp.  Writes a[sp][i][j][h] (float4 over h) to d_out.
__global__ __launch_bounds__(256) void softmax_kernel(
    const float* __restrict__ sl_g, const float* __restrict__ sr_g,
    float* __restrict__ a_out) {
    __shared__ float4 sl[N_], sr[N_], mrow[N_], invs[N_];
    __shared__ float mx1[H_], mx2[H_];
    __shared__ int   id1[H_];

    int sp = blockIdx.x;
    int t = threadIdx.x;
    if (t < 128)       sl[t]       = ((const float4*)sl_g)[sp * N_ + t];
    else               sr[t - 128] = ((const float4*)sr_g)[sp * N_ + (t - 128)];
    __syncthreads();

    if (t < H_) {
        float m1 = -1e30f; int i1 = 0;
        for (int j = 0; j < N_; ++j) {
            float v = ((const float*)&sl[j])[t];
            if (v > m1) { m1 = v; i1 = j; }
        }
        float m2 = -1e30f;
        for (int j = 0; j < N_; ++j)
            if (j != i1) m2 = fmaxf(m2, ((const float*)&sl[j])[t]);
        mx1[t] = m1; mx2[t] = m2; id1[t] = i1;
    }
    __syncthreads();

    {   // pass 1: per-(i,h) max (via monotonicity) and sum
        int i = t & 127, h0 = t >> 7;
        int ha = h0, hb = h0 + 2;
        float sra = ((const float*)&sr[i])[ha];
        float srb = ((const float*)&sr[i])[hb];
        float ma = lrelu(sra + ((id1[ha] == i) ? mx2[ha] : mx1[ha]));
        float mb = lrelu(srb + ((id1[hb] == i) ? mx2[hb] : mx1[hb]));
        float suma = 0.f, sumb = 0.f;
        for (int j = 0; j < N_; ++j) {
            float4 slj = sl[j];
            float ea = lrelu(sra + ((const float*)&slj)[ha]);
            float eb = lrelu(srb + ((const float*)&slj)[hb]);
            float pa = __expf(ea - ma);
            float pb = __expf(eb - mb);
            if (j != i) { suma += pa; sumb += pb; }
        }
        ((float*)&mrow[i])[ha] = ma;  ((float*)&mrow[i])[hb] = mb;
        ((float*)&invs[i])[ha] = 1.f / suma; ((float*)&invs[i])[hb] = 1.f / sumb;
    }
    __syncthreads();

    float4* a_base = (float4*)(a_out + (size_t)sp * (N_ * N_ * H_));
    int jdx = t & 127, half = t >> 7;
    for (int it = 0; it < 64; ++it) {
        int i = it * 2 + half;
        float4 srv = sr[i], m4 = mrow[i], s4 = invs[i], slv = sl[jdx];
        float4 p;
        p.x = __expf(lrelu(srv.x + slv.x) - m4.x) * s4.x;
        p.y = __expf(lrelu(srv.y + slv.y) - m4.y) * s4.y;
        p.z = __expf(lrelu(srv.z + slv.z) - m4.z) * s4.z;
        p.w = __expf(lrelu(srv.w + slv.w) - m4.w) * s4.w;
        if (jdx == i) { p.x = 0.f; p.y = 0.f; p.z = 0.f; p.w = 0.f; }
        a_base[i * N_ + jdx] = p;
    }
}

// ---------------------------------------------------------------------------
// PV via MFMA: one block per sp (512 thr, 8 waves). Per head:
//   stage attn row-tile as bf16 hi/lo [i][j] and G^T [f][j] (XOR-swizzled),
//   acc[i][f] += (ahi+alo)[i][j] x gbf[j][f] with mfma_f32_16x16x32_bf16.
// Head-mean folds into the accumulator; x0.25 at epilogue.
__global__ __launch_bounds__(512) void pv_mfma_kernel(
    const float* __restrict__ a_g, const unsigned short* __restrict__ g,
    float* __restrict__ out) {
    constexpr int PH = 136;                 // LDS pitch (bf16 elems), 272B: 16B-aligned, bank-stride 4
    __shared__ unsigned short ahi[128 * PH];
    __shared__ unsigned short alo[128 * PH];
    __shared__ unsigned short ghT[128 * PH];

    int sp = blockIdx.x;
    int t = threadIdx.x;
    int w = t >> 6, l = t & 63;
    int i0  = (w & 3) * 32;                 // wave output tile: 32 i x 64 f
    int f0w = (w >> 2) * 64;

    const float* a_base = a_g + (size_t)sp * 65536;           // [i][j][h] floats
    const unsigned short* g_base = g + (size_t)sp * 65536;    // [j][h*128+f] bf16

    f32x4 acc[2][4];
#pragma unroll
    for (int m = 0; m < 2; ++m)
#pragma unroll
        for (int n = 0; n < 4; ++n) acc[m][n] = (f32x4){0.f, 0.f, 0.f, 0.f};

    for (int h = 0; h < H_; ++h) {
        if (h) __syncthreads();

        // ---- stage attn tile (hi/lo bf16), [i][j], j-contiguous ----
        {
            int i  = t >> 2;                // 0..127
            int j0 = (t & 3) * 32;
            const float* ap = a_base + ((size_t)i * 128 + j0) * 4 + h;
#pragma unroll
            for (int u = 0; u < 4; ++u) {
                union { unsigned short us[8]; uint4 v; } ph, pl;
#pragma unroll
                for (int e = 0; e < 8; ++e) {
                    float av = ap[(u * 8 + e) * 4];
                    unsigned short hi = f2bf(av);
                    ph.us[e] = hi;
                    pl.us[e] = f2bf(av - bf2f(hi));
                }
                int col = j0 + u * 8;
                *(uint4*)&ahi[i * PH + col] = ph.v;
                *(uint4*)&alo[i * PH + col] = pl.v;
            }
        }
        // ---- stage G^T: 8j x 4f micro-transpose, XOR j-block swizzle ----
        {
            int fq = t & 31;                // f0 = fq*4
            int jq = t >> 5;                // j0 = jq*8 (0..15)
            int f0 = fq * 4, j0 = jq * 8;
            const unsigned short* gp = g_base + h * NH_ + f0;
            unsigned short tr[8][4];
#pragma unroll
            for (int jr = 0; jr < 8; ++jr) {
                uint2 v = *(const uint2*)(gp + (size_t)(j0 + jr) * GC_);
                const unsigned short* pv = (const unsigned short*)&v;
                tr[jr][0] = pv[0]; tr[jr][1] = pv[1]; tr[jr][2] = pv[2]; tr[jr][3] = pv[3];
            }
            int jbase = j0 ^ ((((unsigned)f0 >> 3) & 3) << 3);   // f>>3 constant over fz
#pragma unroll
            for (int fz = 0; fz < 4; ++fz) {
                union { unsigned short us[8]; uint4 v; } pk;
#pragma unroll
                for (int jr = 0; jr < 8; ++jr) pk.us[jr] = tr[jr][fz];
                *(uint4*)&ghT[(f0 + fz) * PH + jbase] = pk.v;
            }
        }
        __syncthreads();

        // ---- MFMA: K = 128 over j ----
#pragma unroll
        for (int k0 = 0; k0 < 128; k0 += 32) {
            int koff = k0 + 8 * (l >> 4);
            uint4 fah[2], fal[2], fbv[4];
#pragma unroll
            for (int m = 0; m < 2; ++m) {
                int row = i0 + m * 16 + (l & 15);
                fah[m] = *(const uint4*)&ahi[row * PH + koff];
                fal[m] = *(const uint4*)&alo[row * PH + koff];
            }
#pragma unroll
            for (int n = 0; n < 4; ++n) {
                int f = f0w + n * 16 + (l & 15);
                int jc = koff ^ (((f >> 3) & 3) << 3);
                fbv[n] = *(const uint4*)&ghT[f * PH + jc];
            }
#pragma unroll
            for (int m = 0; m < 2; ++m)
#pragma unroll
                for (int n = 0; n < 4; ++n) {
                    acc[m][n] = mfma16(fah[m], fbv[n], acc[m][n]);
                    acc[m][n] = mfma16(fal[m], fbv[n], acc[m][n]);
                }
        }
    }

    // ---- epilogue: out[i][sp*128+f] = 0.25 * acc ----
    int g4 = (l >> 4) * 4;
    int c  = l & 15;
#pragma unroll
    for (int m = 0; m < 2; ++m) {
        int ibase = i0 + m * 16 + g4;
#pragma unroll
        for (int n = 0; n < 4; ++n) {
            int f = f0w + n * 16 + c;
#pragma unroll
            for (int q = 0; q < 4; ++q)
                out[(size_t)(ibase + q) * 65536 + (size_t)sp * NH_ + f] = acc[m][n][q] * 0.25f;
        }
    }
}

// ---------------------------------------------------------------------------
extern "C" void kernel_launch(void* const* d_in, const int* in_sizes, int n_in,
                              void* d_out, int out_size, void* d_ws, size_t ws_size,
                              hipStream_t stream) {
    const float* hm = (const float*)d_in[0];
    const float* Wl = (const float*)d_in[1];
    const float* Wr = (const float*)d_in[2];
    const float* aw = (const float*)d_in[3];

    float* out   = (float*)d_out;
    float* a_out = out + OUT_ELEMS;

    char* ws = (char*)d_ws;
    unsigned short* g = (unsigned short*)ws;              // 64 MiB bf16
    float* sl  = (float*)(ws + (size_t)67108864);
    float* sr  = sl + SP_ * N_ * H_;
    float* wls = sr + SP_ * N_ * H_;
    float* wrs = wls + F_ * H_;

    prep_kernel   <<<8,           256, 0, stream>>>(Wl, Wr, aw, wls, wrs);
    score_kernel  <<<ROWS_ / 256, 256, 0, stream>>>(hm, wls, wrs, sl, sr);
    gemm_gr       <<<2048,        256, 0, stream>>>(hm, Wr, g);
    softmax_kernel<<<SP_,         256, 0, stream>>>(sl, sr, a_out);
    pv_mfma_kernel<<<SP_,         512, 0, stream>>>(a_out, g, out);
}

// Round 3
// 248.315 us; speedup vs baseline: 2.2690x; 1.4974x over previous
//
#include <hip/hip_runtime.h>
#include <hip/hip_bf16.h>

#define DI __device__ __forceinline__

namespace {
constexpr int N_ = 128, S_ = 32, P_ = 16, F_ = 256, H_ = 4, NH_ = 128;
constexpr int SP_ = S_ * P_;          // 512
constexpr int ROWS_ = N_ * SP_;       // 65536
constexpr int GC_ = H_ * NH_;         // 512
constexpr float SLOPE_ = 0.2f;
constexpr int OUT_ELEMS = N_ * SP_ * NH_;    // 8,388,608
}

DI float lrelu(float x) { return x >= 0.f ? x : SLOPE_ * x; }

DI unsigned short f2bf(float x) {
    unsigned int u = __float_as_uint(x);
    u += 0x7fffu + ((u >> 16) & 1u);
    return (unsigned short)(u >> 16);
}
DI float bf2f(unsigned short b) { return __uint_as_float(((unsigned int)b) << 16); }

typedef __bf16 bf16x8 __attribute__((ext_vector_type(8)));
typedef float  f32x4  __attribute__((ext_vector_type(4)));

DI f32x4 mfma16(uint4 a, uint4 b, f32x4 c) {
    return __builtin_amdgcn_mfma_f32_16x16x32_bf16(
        __builtin_bit_cast(bf16x8, a), __builtin_bit_cast(bf16x8, b), c, 0, 0, 0);
}

// ---------------------------------------------------------------------------
// prep: wl_s[f][h] = sum_nh W_l[f][h*128+nh]*aw[nh];  wr_s likewise with aw[128+]
__global__ __launch_bounds__(256) void prep_kernel(
    const float* __restrict__ Wl, const float* __restrict__ Wr,
    const float* __restrict__ aw, float* __restrict__ wls, float* __restrict__ wrs) {
    int t = blockIdx.x * 256 + threadIdx.x;   // 0..2047
    int which = t >> 10;                       // 0 -> wl, 1 -> wr
    int f = (t & 1023) >> 2;
    int h = t & 3;
    const float* W = which ? Wr : Wl;
    const float* a = aw + which * NH_;
    const float* wrow = W + (size_t)f * GC_ + h * NH_;
    float s = 0.f;
    for (int k = 0; k < NH_; ++k) s += wrow[k] * a[k];
    (which ? wrs : wls)[f * H_ + h] = s;
}

// ---------------------------------------------------------------------------
// prep_bt: split Wr into bf16 hi/lo in TRANSPOSED layout bt[col][k]
__global__ __launch_bounds__(256) void prep_bt(
    const float* __restrict__ Wr, unsigned short* __restrict__ bth,
    unsigned short* __restrict__ btl) {
    int t = blockIdx.x * 256 + threadIdx.x;   // 0..16383
    int col = t >> 5, k0 = (t & 31) * 8;
    union { unsigned short us[8]; uint4 v; } ph, pl;
#pragma unroll
    for (int e = 0; e < 8; ++e) {
        float v = Wr[(size_t)(k0 + e) * GC_ + col];
        unsigned short hi = f2bf(v);
        ph.us[e] = hi;
        pl.us[e] = f2bf(v - bf2f(hi));
    }
    *(uint4*)&bth[col * F_ + k0] = ph.v;
    *(uint4*)&btl[col * F_ + k0] = pl.v;
}

// ---------------------------------------------------------------------------
// scores: one thread per row r = n*512 + sp of h.  sl/sr layout: [sp][n][h]
__global__ __launch_bounds__(256) void score_kernel(
    const float* __restrict__ hm, const float* __restrict__ wls,
    const float* __restrict__ wrs, float* __restrict__ sl, float* __restrict__ sr) {
    int r = blockIdx.x * 256 + threadIdx.x;    // 0..65535
    const float4* hr  = (const float4*)(hm + (size_t)r * F_);
    const float4* wl4 = (const float4*)wls;    // [f] -> 4 heads
    const float4* wr4 = (const float4*)wrs;
    float4 al = {0.f,0.f,0.f,0.f}, ar = {0.f,0.f,0.f,0.f};
    for (int f0 = 0; f0 < F_; f0 += 4) {
        float4 hv = hr[f0 >> 2];
        float hx[4] = {hv.x, hv.y, hv.z, hv.w};
#pragma unroll
        for (int u = 0; u < 4; ++u) {
            float4 wl = wl4[f0 + u], wr = wr4[f0 + u];
            al.x += hx[u] * wl.x; al.y += hx[u] * wl.y;
            al.z += hx[u] * wl.z; al.w += hx[u] * wl.w;
            ar.x += hx[u] * wr.x; ar.y += hx[u] * wr.y;
            ar.z += hx[u] * wr.z; ar.w += hx[u] * wr.w;
        }
    }
    int n = r >> 9, sp = r & 511;
    ((float4*)sl)[sp * N_ + n] = al;
    ((float4*)sr)[sp * N_ + n] = ar;
}

// ---------------------------------------------------------------------------
// g_r GEMM via split-bf16 MFMA: (65536 x 256) @ (256 x 512), out bf16 [sp][n][col].
// 512 blocks of 512 threads; block = 128 rows x 512 cols; wave tile 128 x 64.
// A staged hi/lo in LDS per 64-K step; B frags loaded from L2 (pre-transposed).
__global__ __launch_bounds__(512) void gemm_mfma(
    const float* __restrict__ hm, const unsigned short* __restrict__ bth,
    const unsigned short* __restrict__ btl, unsigned short* __restrict__ g) {
    constexpr int PA = 72;   // LDS pitch (bf16): 144B rows -> 2-way (free) frag reads
    __shared__ unsigned short Ahi[128 * PA];
    __shared__ unsigned short Alo[128 * PA];

    int rb = blockIdx.x;                 // 0..511
    int t = threadIdx.x;
    int w = t >> 6, l = t & 63;
    int colw = w * 64;
    int ls = l & 15, kg = l >> 4;

    f32x4 acc[8][4];
#pragma unroll
    for (int m = 0; m < 8; ++m)
#pragma unroll
        for (int n = 0; n < 4; ++n) acc[m][n] = (f32x4){0.f, 0.f, 0.f, 0.f};

    const float* abase = hm + (size_t)rb * 128 * F_;

    for (int step = 0; step < 4; ++step) {
        int k0s = step * 64;
        if (step) __syncthreads();
        // ---- stage A-tile (128 rows x 64 k) as hi/lo bf16 ----
#pragma unroll
        for (int u = 0; u < 2; ++u) {
            int gi = t + u * 512;
            int row = gi >> 3, kc = (gi & 7) * 8;
            const float* ap = abase + (size_t)row * F_ + k0s + kc;
            float4 a0 = *(const float4*)ap;
            float4 a1 = *(const float4*)(ap + 4);
            float av[8] = {a0.x, a0.y, a0.z, a0.w, a1.x, a1.y, a1.z, a1.w};
            union { unsigned short us[8]; uint4 v; } ph, pl;
#pragma unroll
            for (int e = 0; e < 8; ++e) {
                unsigned short hi = f2bf(av[e]);
                ph.us[e] = hi;
                pl.us[e] = f2bf(av[e] - bf2f(hi));
            }
            *(uint4*)&Ahi[row * PA + kc] = ph.v;
            *(uint4*)&Alo[row * PA + kc] = pl.v;
        }
        __syncthreads();

#pragma unroll
        for (int half = 0; half < 2; ++half) {
            int kglob = k0s + half * 32 + kg * 8;
            int kloc  = half * 32 + kg * 8;
            uint4 fbh[4], fbl[4];
#pragma unroll
            for (int n = 0; n < 4; ++n) {
                int c = colw + n * 16 + ls;
                fbh[n] = *(const uint4*)&bth[(size_t)c * F_ + kglob];
                fbl[n] = *(const uint4*)&btl[(size_t)c * F_ + kglob];
            }
#pragma unroll
            for (int m = 0; m < 8; ++m) {
                int row = m * 16 + ls;
                uint4 fah = *(const uint4*)&Ahi[row * PA + kloc];
                uint4 fal = *(const uint4*)&Alo[row * PA + kloc];
#pragma unroll
                for (int n = 0; n < 4; ++n) {
                    acc[m][n] = mfma16(fbh[n], fah, acc[m][n]);   // hi*hi
                    acc[m][n] = mfma16(fbl[n], fah, acc[m][n]);   // lo_B*hi_A
                    acc[m][n] = mfma16(fbh[n], fal, acc[m][n]);   // hi_B*lo_A
                }
            }
        }
    }

    // ---- epilogue: D[c][r] layout -> 4 contiguous cols per lane (8B stores) ----
    int n_out = rb >> 2, spb = (rb & 3) * 128;
#pragma unroll
    for (int m = 0; m < 8; ++m) {
        int sp = spb + m * 16 + ls;
        unsigned short* gr = g + (size_t)sp * 65536 + (size_t)n_out * GC_ + colw + kg * 4;
#pragma unroll
        for (int n = 0; n < 4; ++n) {
            union { unsigned short us[4]; uint2 v; } pk;
#pragma unroll
            for (int q = 0; q < 4; ++q) pk.us[q] = f2bf(acc[m][n][q]);
            *(uint2*)(gr + n * 16) = pk.v;
        }
    }
}

// ---------------------------------------------------------------------------
// softmax: one block per sp.  Writes a[sp][i][j][h] (float4 over h) to d_out.
__global__ __launch_bounds__(256) void softmax_kernel(
    const float* __restrict__ sl_g, const float* __restrict__ sr_g,
    float* __restrict__ a_out) {
    __shared__ float4 sl[N_], sr[N_], mrow[N_], invs[N_];
    __shared__ float mx1[H_], mx2[H_];
    __shared__ int   id1[H_];

    int sp = blockIdx.x;
    int t = threadIdx.x;
    if (t < 128)       sl[t]       = ((const float4*)sl_g)[sp * N_ + t];
    else               sr[t - 128] = ((const float4*)sr_g)[sp * N_ + (t - 128)];
    __syncthreads();

    if (t < H_) {
        float m1 = -1e30f; int i1 = 0;
        for (int j = 0; j < N_; ++j) {
            float v = ((const float*)&sl[j])[t];
            if (v > m1) { m1 = v; i1 = j; }
        }
        float m2 = -1e30f;
        for (int j = 0; j < N_; ++j)
            if (j != i1) m2 = fmaxf(m2, ((const float*)&sl[j])[t]);
        mx1[t] = m1; mx2[t] = m2; id1[t] = i1;
    }
    __syncthreads();

    {   // pass 1: per-(i,h) max (via monotonicity) and sum
        int i = t & 127, h0 = t >> 7;
        int ha = h0, hb = h0 + 2;
        float sra = ((const float*)&sr[i])[ha];
        float srb = ((const float*)&sr[i])[hb];
        float ma = lrelu(sra + ((id1[ha] == i) ? mx2[ha] : mx1[ha]));
        float mb = lrelu(srb + ((id1[hb] == i) ? mx2[hb] : mx1[hb]));
        float suma = 0.f, sumb = 0.f;
        for (int j = 0; j < N_; ++j) {
            float4 slj = sl[j];
            float ea = lrelu(sra + ((const float*)&slj)[ha]);
            float eb = lrelu(srb + ((const float*)&slj)[hb]);
            float pa = __expf(ea - ma);
            float pb = __expf(eb - mb);
            if (j != i) { suma += pa; sumb += pb; }
        }
        ((float*)&mrow[i])[ha] = ma;  ((float*)&mrow[i])[hb] = mb;
        ((float*)&invs[i])[ha] = 1.f / suma; ((float*)&invs[i])[hb] = 1.f / sumb;
    }
    __syncthreads();

    float4* a_base = (float4*)(a_out + (size_t)sp * (N_ * N_ * H_));
    int jdx = t & 127, half = t >> 7;
    for (int it = 0; it < 64; ++it) {
        int i = it * 2 + half;
        float4 srv = sr[i], m4 = mrow[i], s4 = invs[i], slv = sl[jdx];
        float4 p;
        p.x = __expf(lrelu(srv.x + slv.x) - m4.x) * s4.x;
        p.y = __expf(lrelu(srv.y + slv.y) - m4.y) * s4.y;
        p.z = __expf(lrelu(srv.z + slv.z) - m4.z) * s4.z;
        p.w = __expf(lrelu(srv.w + slv.w) - m4.w) * s4.w;
        if (jdx == i) { p.x = 0.f; p.y = 0.f; p.z = 0.f; p.w = 0.f; }
        a_base[i * N_ + jdx] = p;
    }
}

// ---------------------------------------------------------------------------
// PV via MFMA: one block per sp (512 thr, 8 waves).
__global__ __launch_bounds__(512) void pv_mfma_kernel(
    const float* __restrict__ a_g, const unsigned short* __restrict__ g,
    float* __restrict__ out) {
    constexpr int PH = 136;
    __shared__ unsigned short ahi[128 * PH];
    __shared__ unsigned short alo[128 * PH];
    __shared__ unsigned short ghT[128 * PH];

    int sp = blockIdx.x;
    int t = threadIdx.x;
    int w = t >> 6, l = t & 63;
    int i0  = (w & 3) * 32;
    int f0w = (w >> 2) * 64;

    const float* a_base = a_g + (size_t)sp * 65536;
    const unsigned short* g_base = g + (size_t)sp * 65536;

    f32x4 acc[2][4];
#pragma unroll
    for (int m = 0; m < 2; ++m)
#pragma unroll
        for (int n = 0; n < 4; ++n) acc[m][n] = (f32x4){0.f, 0.f, 0.f, 0.f};

    for (int h = 0; h < H_; ++h) {
        if (h) __syncthreads();

        {   // stage attn tile (hi/lo bf16), [i][j]
            int i  = t >> 2;
            int j0 = (t & 3) * 32;
            const float* ap = a_base + ((size_t)i * 128 + j0) * 4 + h;
#pragma unroll
            for (int u = 0; u < 4; ++u) {
                union { unsigned short us[8]; uint4 v; } ph, pl;
#pragma unroll
                for (int e = 0; e < 8; ++e) {
                    float av = ap[(u * 8 + e) * 4];
                    unsigned short hi = f2bf(av);
                    ph.us[e] = hi;
                    pl.us[e] = f2bf(av - bf2f(hi));
                }
                int col = j0 + u * 8;
                *(uint4*)&ahi[i * PH + col] = ph.v;
                *(uint4*)&alo[i * PH + col] = pl.v;
            }
        }
        {   // stage G^T with 8j x 4f micro-transpose + XOR j-block swizzle
            int fq = t & 31;
            int jq = t >> 5;
            int f0 = fq * 4, j0 = jq * 8;
            const unsigned short* gp = g_base + h * NH_ + f0;
            unsigned short tr[8][4];
#pragma unroll
            for (int jr = 0; jr < 8; ++jr) {
                uint2 v = *(const uint2*)(gp + (size_t)(j0 + jr) * GC_);
                const unsigned short* pv = (const unsigned short*)&v;
                tr[jr][0] = pv[0]; tr[jr][1] = pv[1]; tr[jr][2] = pv[2]; tr[jr][3] = pv[3];
            }
            int jbase = j0 ^ ((((unsigned)f0 >> 3) & 3) << 3);
#pragma unroll
            for (int fz = 0; fz < 4; ++fz) {
                union { unsigned short us[8]; uint4 v; } pk;
#pragma unroll
                for (int jr = 0; jr < 8; ++jr) pk.us[jr] = tr[jr][fz];
                *(uint4*)&ghT[(f0 + fz) * PH + jbase] = pk.v;
            }
        }
        __syncthreads();

#pragma unroll
        for (int k0 = 0; k0 < 128; k0 += 32) {
            int koff = k0 + 8 * (l >> 4);
            uint4 fah[2], fal[2], fbv[4];
#pragma unroll
            for (int m = 0; m < 2; ++m) {
                int row = i0 + m * 16 + (l & 15);
                fah[m] = *(const uint4*)&ahi[row * PH + koff];
                fal[m] = *(const uint4*)&alo[row * PH + koff];
            }
#pragma unroll
            for (int n = 0; n < 4; ++n) {
                int f = f0w + n * 16 + (l & 15);
                int jc = koff ^ (((f >> 3) & 3) << 3);
                fbv[n] = *(const uint4*)&ghT[f * PH + jc];
            }
#pragma unroll
            for (int m = 0; m < 2; ++m)
#pragma unroll
                for (int n = 0; n < 4; ++n) {
                    acc[m][n] = mfma16(fah[m], fbv[n], acc[m][n]);
                    acc[m][n] = mfma16(fal[m], fbv[n], acc[m][n]);
                }
        }
    }

    int g4 = (l >> 4) * 4;
    int c  = l & 15;
#pragma unroll
    for (int m = 0; m < 2; ++m) {
        int ibase = i0 + m * 16 + g4;
#pragma unroll
        for (int n = 0; n < 4; ++n) {
            int f = f0w + n * 16 + c;
#pragma unroll
            for (int q = 0; q < 4; ++q)
                out[(size_t)(ibase + q) * 65536 + (size_t)sp * NH_ + f] = acc[m][n][q] * 0.25f;
        }
    }
}

// ---------------------------------------------------------------------------
extern "C" void kernel_launch(void* const* d_in, const int* in_sizes, int n_in,
                              void* d_out, int out_size, void* d_ws, size_t ws_size,
                              hipStream_t stream) {
    const float* hm = (const float*)d_in[0];
    const float* Wl = (const float*)d_in[1];
    const float* Wr = (const float*)d_in[2];
    const float* aw = (const float*)d_in[3];

    float* out   = (float*)d_out;
    float* a_out = out + OUT_ELEMS;

    char* ws = (char*)d_ws;
    unsigned short* g = (unsigned short*)ws;              // 64 MiB bf16
    float* sl  = (float*)(ws + (size_t)67108864);
    float* sr  = sl + SP_ * N_ * H_;
    float* wls = sr + SP_ * N_ * H_;
    float* wrs = wls + F_ * H_;
    unsigned short* bth = (unsigned short*)(ws + (size_t)67108864 + 2113536);
    unsigned short* btl = bth + GC_ * F_;                 // 512*256 each

    prep_kernel   <<<8,           256, 0, stream>>>(Wl, Wr, aw, wls, wrs);
    prep_bt       <<<64,          256, 0, stream>>>(Wr, bth, btl);
    score_kernel  <<<ROWS_ / 256, 256, 0, stream>>>(hm, wls, wrs, sl, sr);
    gemm_mfma     <<<512,         512, 0, stream>>>(hm, bth, btl, g);
    softmax_kernel<<<SP_,         256, 0, stream>>>(sl, sr, a_out);
    pv_mfma_kernel<<<SP_,         512, 0, stream>>>(a_out, g, out);
}

// Round 4
// 220.413 us; speedup vs baseline: 2.5562x; 1.1266x over previous
//
#include <hip/hip_runtime.h>
#include <hip/hip_bf16.h>

#define DI __device__ __forceinline__

namespace {
constexpr int N_ = 128, S_ = 32, P_ = 16, F_ = 256, H_ = 4, NH_ = 128;
constexpr int SP_ = S_ * P_;          // 512
constexpr int ROWS_ = N_ * SP_;       // 65536
constexpr int GC_ = H_ * NH_;         // 512
constexpr float SLOPE_ = 0.2f;
constexpr int OUT_ELEMS = N_ * SP_ * NH_;    // 8,388,608
}

DI float lrelu(float x) { return x >= 0.f ? x : SLOPE_ * x; }

DI unsigned short f2bf(float x) {
    unsigned int u = __float_as_uint(x);
    u += 0x7fffu + ((u >> 16) & 1u);
    return (unsigned short)(u >> 16);
}
DI float bf2f(unsigned short b) { return __uint_as_float(((unsigned int)b) << 16); }

typedef __bf16 bf16x8 __attribute__((ext_vector_type(8)));
typedef float  f32x4  __attribute__((ext_vector_type(4)));

DI f32x4 mfma16(uint4 a, uint4 b, f32x4 c) {
    return __builtin_amdgcn_mfma_f32_16x16x32_bf16(
        __builtin_bit_cast(bf16x8, a), __builtin_bit_cast(bf16x8, b), c, 0, 0, 0);
}

// ---------------------------------------------------------------------------
// prep: wl_s[f][h] = sum_nh W_l[f][h*128+nh]*aw[nh];  wr_s likewise with aw[128+]
__global__ __launch_bounds__(256) void prep_kernel(
    const float* __restrict__ Wl, const float* __restrict__ Wr,
    const float* __restrict__ aw, float* __restrict__ wls, float* __restrict__ wrs) {
    int t = blockIdx.x * 256 + threadIdx.x;   // 0..2047
    int which = t >> 10;                       // 0 -> wl, 1 -> wr
    int f = (t & 1023) >> 2;
    int h = t & 3;
    const float* W = which ? Wr : Wl;
    const float* a = aw + which * NH_;
    const float* wrow = W + (size_t)f * GC_ + h * NH_;
    float s = 0.f;
    for (int k = 0; k < NH_; ++k) s += wrow[k] * a[k];
    (which ? wrs : wls)[f * H_ + h] = s;
}

// ---------------------------------------------------------------------------
// prep_bt: split Wr into bf16 hi/lo in TRANSPOSED layout bt[col][k]
__global__ __launch_bounds__(256) void prep_bt(
    const float* __restrict__ Wr, unsigned short* __restrict__ bth,
    unsigned short* __restrict__ btl) {
    int t = blockIdx.x * 256 + threadIdx.x;   // 0..16383
    int col = t >> 5, k0 = (t & 31) * 8;
    union { unsigned short us[8]; uint4 v; } ph, pl;
#pragma unroll
    for (int e = 0; e < 8; ++e) {
        float v = Wr[(size_t)(k0 + e) * GC_ + col];
        unsigned short hi = f2bf(v);
        ph.us[e] = hi;
        pl.us[e] = f2bf(v - bf2f(hi));
    }
    *(uint4*)&bth[col * F_ + k0] = ph.v;
    *(uint4*)&btl[col * F_ + k0] = pl.v;
}

// ---------------------------------------------------------------------------
// scores: one thread per row r = n*512 + sp of h.  sl/sr layout: [sp][n][h]
__global__ __launch_bounds__(256) void score_kernel(
    const float* __restrict__ hm, const float* __restrict__ wls,
    const float* __restrict__ wrs, float* __restrict__ sl, float* __restrict__ sr) {
    int r = blockIdx.x * 256 + threadIdx.x;    // 0..65535
    const float4* hr  = (const float4*)(hm + (size_t)r * F_);
    const float4* wl4 = (const float4*)wls;    // [f] -> 4 heads
    const float4* wr4 = (const float4*)wrs;
    float4 al = {0.f,0.f,0.f,0.f}, ar = {0.f,0.f,0.f,0.f};
    for (int f0 = 0; f0 < F_; f0 += 4) {
        float4 hv = hr[f0 >> 2];
        float hx[4] = {hv.x, hv.y, hv.z, hv.w};
#pragma unroll
        for (int u = 0; u < 4; ++u) {
            float4 wl = wl4[f0 + u], wr = wr4[f0 + u];
            al.x += hx[u] * wl.x; al.y += hx[u] * wl.y;
            al.z += hx[u] * wl.z; al.w += hx[u] * wl.w;
            ar.x += hx[u] * wr.x; ar.y += hx[u] * wr.y;
            ar.z += hx[u] * wr.z; ar.w += hx[u] * wr.w;
        }
    }
    int n = r >> 9, sp = r & 511;
    ((float4*)sl)[sp * N_ + n] = al;
    ((float4*)sr)[sp * N_ + n] = ar;
}

// ---------------------------------------------------------------------------
// g_r GEMM via split-bf16 MFMA: (65536 x 256) @ (256 x 512), out bf16 [sp][n][col].
__global__ __launch_bounds__(512) void gemm_mfma(
    const float* __restrict__ hm, const unsigned short* __restrict__ bth,
    const unsigned short* __restrict__ btl, unsigned short* __restrict__ g) {
    constexpr int PA = 72;
    __shared__ unsigned short Ahi[128 * PA];
    __shared__ unsigned short Alo[128 * PA];

    int rb = blockIdx.x;
    int t = threadIdx.x;
    int w = t >> 6, l = t & 63;
    int colw = w * 64;
    int ls = l & 15, kg = l >> 4;

    f32x4 acc[8][4];
#pragma unroll
    for (int m = 0; m < 8; ++m)
#pragma unroll
        for (int n = 0; n < 4; ++n) acc[m][n] = (f32x4){0.f, 0.f, 0.f, 0.f};

    const float* abase = hm + (size_t)rb * 128 * F_;

    for (int step = 0; step < 4; ++step) {
        int k0s = step * 64;
        if (step) __syncthreads();
#pragma unroll
        for (int u = 0; u < 2; ++u) {
            int gi = t + u * 512;
            int row = gi >> 3, kc = (gi & 7) * 8;
            const float* ap = abase + (size_t)row * F_ + k0s + kc;
            float4 a0 = *(const float4*)ap;
            float4 a1 = *(const float4*)(ap + 4);
            float av[8] = {a0.x, a0.y, a0.z, a0.w, a1.x, a1.y, a1.z, a1.w};
            union { unsigned short us[8]; uint4 v; } ph, pl;
#pragma unroll
            for (int e = 0; e < 8; ++e) {
                unsigned short hi = f2bf(av[e]);
                ph.us[e] = hi;
                pl.us[e] = f2bf(av[e] - bf2f(hi));
            }
            *(uint4*)&Ahi[row * PA + kc] = ph.v;
            *(uint4*)&Alo[row * PA + kc] = pl.v;
        }
        __syncthreads();

#pragma unroll
        for (int half = 0; half < 2; ++half) {
            int kglob = k0s + half * 32 + kg * 8;
            int kloc  = half * 32 + kg * 8;
            uint4 fbh[4], fbl[4];
#pragma unroll
            for (int n = 0; n < 4; ++n) {
                int c = colw + n * 16 + ls;
                fbh[n] = *(const uint4*)&bth[(size_t)c * F_ + kglob];
                fbl[n] = *(const uint4*)&btl[(size_t)c * F_ + kglob];
            }
#pragma unroll
            for (int m = 0; m < 8; ++m) {
                int row = m * 16 + ls;
                uint4 fah = *(const uint4*)&Ahi[row * PA + kloc];
                uint4 fal = *(const uint4*)&Alo[row * PA + kloc];
#pragma unroll
                for (int n = 0; n < 4; ++n) {
                    acc[m][n] = mfma16(fbh[n], fah, acc[m][n]);
                    acc[m][n] = mfma16(fbl[n], fah, acc[m][n]);
                    acc[m][n] = mfma16(fbh[n], fal, acc[m][n]);
                }
            }
        }
    }

    int n_out = rb >> 2, spb = (rb & 3) * 128;
#pragma unroll
    for (int m = 0; m < 8; ++m) {
        int sp = spb + m * 16 + ls;
        unsigned short* gr = g + (size_t)sp * 65536 + (size_t)n_out * GC_ + colw + kg * 4;
#pragma unroll
        for (int n = 0; n < 4; ++n) {
            union { unsigned short us[4]; uint2 v; } pk;
#pragma unroll
            for (int q = 0; q < 4; ++q) pk.us[q] = f2bf(acc[m][n][q]);
            *(uint2*)(gr + n * 16) = pk.v;
        }
    }
}

// ---------------------------------------------------------------------------
// Fused softmax + PV: one block per sp (512 thr, 8 waves).
// h==0 phase: compute float4 (all heads) p, write a_out coalesced, deposit
// head-0 bf16 hi/lo to LDS. h>=1: recompute that head's p (32 exps/thread),
// deposit. Each head phase stages ghT and runs the MFMA K=128 loop.
__global__ __launch_bounds__(512) void smpv_kernel(
    const float* __restrict__ sl_g, const float* __restrict__ sr_g,
    const unsigned short* __restrict__ g,
    float* __restrict__ a_out, float* __restrict__ out) {
    constexpr int PH = 136;
    __shared__ unsigned short ahi[128 * PH];
    __shared__ unsigned short alo[128 * PH];
    __shared__ unsigned short ghT[128 * PH];
    __shared__ float4 sl4[N_], sr4[N_], mrow[N_], invs[N_];
    __shared__ float mx1[H_], mx2[H_];
    __shared__ int   id1[H_];

    int sp = blockIdx.x;
    int t = threadIdx.x;
    int w = t >> 6, l = t & 63;
    int i0  = (w & 3) * 32;
    int f0w = (w >> 2) * 64;

    if (t < 128)           sl4[t]       = ((const float4*)sl_g)[sp * N_ + t];
    else if (t < 256)      sr4[t - 128] = ((const float4*)sr_g)[sp * N_ + (t - 128)];
    __syncthreads();

    if (t < H_) {
        float m1 = -1e30f; int i1 = 0;
        for (int j = 0; j < N_; ++j) {
            float v = ((const float*)&sl4[j])[t];
            if (v > m1) { m1 = v; i1 = j; }
        }
        float m2 = -1e30f;
        for (int j = 0; j < N_; ++j)
            if (j != i1) m2 = fmaxf(m2, ((const float*)&sl4[j])[t]);
        mx1[t] = m1; mx2[t] = m2; id1[t] = i1;
    }
    __syncthreads();

    {   // pass 1: per-(i,h) max (monotonicity) and inv-sum
        int i = t & 127, h = t >> 7;
        float sri = ((const float*)&sr4[i])[h];
        float m = lrelu(sri + ((id1[h] == i) ? mx2[h] : mx1[h]));
        float sum = 0.f;
        for (int j = 0; j < N_; ++j) {
            float e = lrelu(sri + ((const float*)&sl4[j])[h]);
            float p = __expf(e - m);
            if (j != i) sum += p;
        }
        ((float*)&mrow[i])[h] = m;
        ((float*)&invs[i])[h] = 1.f / sum;
    }
    __syncthreads();

    const unsigned short* g_base = g + (size_t)sp * 65536;
    float4* a_base = (float4*)(a_out + (size_t)sp * 65536);

    f32x4 acc[2][4];
#pragma unroll
    for (int m = 0; m < 2; ++m)
#pragma unroll
        for (int n = 0; n < 4; ++n) acc[m][n] = (f32x4){0.f, 0.f, 0.f, 0.f};

    for (int h = 0; h < H_; ++h) {
        if (h) __syncthreads();

        {   // a-tile compute + LDS deposit (+ coalesced a_out write on h==0)
            int i = t >> 2, j0 = (t & 3) * 32;
            float4 srv = sr4[i], m4 = mrow[i], s4 = invs[i];
            if (h == 0) {
#pragma unroll
                for (int u = 0; u < 4; ++u) {
                    union { unsigned short us[8]; uint4 v; } ph_, pl_;
#pragma unroll
                    for (int e = 0; e < 8; ++e) {
                        int j = j0 + u * 8 + e;
                        float4 slv = sl4[j];
                        float4 p;
                        p.x = __expf(lrelu(srv.x + slv.x) - m4.x) * s4.x;
                        p.y = __expf(lrelu(srv.y + slv.y) - m4.y) * s4.y;
                        p.z = __expf(lrelu(srv.z + slv.z) - m4.z) * s4.z;
                        p.w = __expf(lrelu(srv.w + slv.w) - m4.w) * s4.w;
                        if (j == i) { p.x = 0.f; p.y = 0.f; p.z = 0.f; p.w = 0.f; }
                        a_base[i * N_ + j] = p;
                        unsigned short hi = f2bf(p.x);
                        ph_.us[e] = hi;
                        pl_.us[e] = f2bf(p.x - bf2f(hi));
                    }
                    *(uint4*)&ahi[i * PH + j0 + u * 8] = ph_.v;
                    *(uint4*)&alo[i * PH + j0 + u * 8] = pl_.v;
                }
            } else {
                float sri = ((const float*)&srv)[h];
                float m = ((const float*)&m4)[h], s = ((const float*)&s4)[h];
#pragma unroll
                for (int u = 0; u < 4; ++u) {
                    union { unsigned short us[8]; uint4 v; } ph_, pl_;
#pragma unroll
                    for (int e = 0; e < 8; ++e) {
                        int j = j0 + u * 8 + e;
                        float p = (j == i) ? 0.f
                                : __expf(lrelu(sri + ((const float*)&sl4[j])[h]) - m) * s;
                        unsigned short hi = f2bf(p);
                        ph_.us[e] = hi;
                        pl_.us[e] = f2bf(p - bf2f(hi));
                    }
                    *(uint4*)&ahi[i * PH + j0 + u * 8] = ph_.v;
                    *(uint4*)&alo[i * PH + j0 + u * 8] = pl_.v;
                }
            }
        }
        {   // stage G^T head h: 8j x 4f micro-transpose + XOR j-block swizzle
            int fq = t & 31;
            int jq = t >> 5;          // 0..15
            int f0 = fq * 4, j0 = jq * 8;
            const unsigned short* gp = g_base + h * NH_ + f0;
            unsigned short tr[8][4];
#pragma unroll
            for (int jr = 0; jr < 8; ++jr) {
                uint2 v = *(const uint2*)(gp + (size_t)(j0 + jr) * GC_);
                const unsigned short* pv = (const unsigned short*)&v;
                tr[jr][0] = pv[0]; tr[jr][1] = pv[1]; tr[jr][2] = pv[2]; tr[jr][3] = pv[3];
            }
            int jbase = j0 ^ ((((unsigned)f0 >> 3) & 3) << 3);
#pragma unroll
            for (int fz = 0; fz < 4; ++fz) {
                union { unsigned short us[8]; uint4 v; } pk;
#pragma unroll
                for (int jr = 0; jr < 8; ++jr) pk.us[jr] = tr[jr][fz];
                *(uint4*)&ghT[(f0 + fz) * PH + jbase] = pk.v;
            }
        }
        __syncthreads();

        // MFMA: K = 128 over j
#pragma unroll
        for (int k0 = 0; k0 < 128; k0 += 32) {
            int koff = k0 + 8 * (l >> 4);
            uint4 fah[2], fal[2], fbv[4];
#pragma unroll
            for (int m = 0; m < 2; ++m) {
                int row = i0 + m * 16 + (l & 15);
                fah[m] = *(const uint4*)&ahi[row * PH + koff];
                fal[m] = *(const uint4*)&alo[row * PH + koff];
            }
#pragma unroll
            for (int n = 0; n < 4; ++n) {
                int f = f0w + n * 16 + (l & 15);
                int jc = koff ^ (((f >> 3) & 3) << 3);
                fbv[n] = *(const uint4*)&ghT[f * PH + jc];
            }
#pragma unroll
            for (int m = 0; m < 2; ++m)
#pragma unroll
                for (int n = 0; n < 4; ++n) {
                    acc[m][n] = mfma16(fah[m], fbv[n], acc[m][n]);
                    acc[m][n] = mfma16(fal[m], fbv[n], acc[m][n]);
                }
        }
    }

    int g4 = (l >> 4) * 4;
    int c  = l & 15;
#pragma unroll
    for (int m = 0; m < 2; ++m) {
        int ibase = i0 + m * 16 + g4;
#pragma unroll
        for (int n = 0; n < 4; ++n) {
            int f = f0w + n * 16 + c;
#pragma unroll
            for (int q = 0; q < 4; ++q)
                out[(size_t)(ibase + q) * 65536 + (size_t)sp * NH_ + f] = acc[m][n][q] * 0.25f;
        }
    }
}

// ---------------------------------------------------------------------------
extern "C" void kernel_launch(void* const* d_in, const int* in_sizes, int n_in,
                              void* d_out, int out_size, void* d_ws, size_t ws_size,
                              hipStream_t stream) {
    const float* hm = (const float*)d_in[0];
    const float* Wl = (const float*)d_in[1];
    const float* Wr = (const float*)d_in[2];
    const float* aw = (const float*)d_in[3];

    float* out   = (float*)d_out;
    float* a_out = out + OUT_ELEMS;

    char* ws = (char*)d_ws;
    unsigned short* g = (unsigned short*)ws;              // 64 MiB bf16
    float* sl  = (float*)(ws + (size_t)67108864);
    float* sr  = sl + SP_ * N_ * H_;
    float* wls = sr + SP_ * N_ * H_;
    float* wrs = wls + F_ * H_;
    unsigned short* bth = (unsigned short*)(ws + (size_t)67108864 + 2113536);
    unsigned short* btl = bth + GC_ * F_;                 // 512*256 each

    prep_kernel   <<<8,           256, 0, stream>>>(Wl, Wr, aw, wls, wrs);
    prep_bt       <<<64,          256, 0, stream>>>(Wr, bth, btl);
    score_kernel  <<<ROWS_ / 256, 256, 0, stream>>>(hm, wls, wrs, sl, sr);
    gemm_mfma     <<<512,         512, 0, stream>>>(hm, bth, btl, g);
    smpv_kernel   <<<SP_,         512, 0, stream>>>(sl, sr, g, a_out, out);
}

// Round 5
// 196.421 us; speedup vs baseline: 2.8684x; 1.1221x over previous
//
#include <hip/hip_runtime.h>
#include <hip/hip_bf16.h>

#define DI __device__ __forceinline__

namespace {
constexpr int N_ = 128, S_ = 32, P_ = 16, F_ = 256, H_ = 4, NH_ = 128;
constexpr int SP_ = S_ * P_;          // 512
constexpr int ROWS_ = N_ * SP_;       // 65536
constexpr int GC_ = H_ * NH_;         // 512
constexpr float SLOPE_ = 0.2f;
constexpr int OUT_ELEMS = N_ * SP_ * NH_;    // 8,388,608
}

DI float lrelu(float x) { return x >= 0.f ? x : SLOPE_ * x; }

DI unsigned short f2bf(float x) {
    unsigned int u = __float_as_uint(x);
    u += 0x7fffu + ((u >> 16) & 1u);
    return (unsigned short)(u >> 16);
}
DI float bf2f(unsigned short b) { return __uint_as_float(((unsigned int)b) << 16); }

typedef __bf16 bf16x8 __attribute__((ext_vector_type(8)));
typedef float  f32x4  __attribute__((ext_vector_type(4)));

DI f32x4 mfma16(uint4 a, uint4 b, f32x4 c) {
    return __builtin_amdgcn_mfma_f32_16x16x32_bf16(
        __builtin_bit_cast(bf16x8, a), __builtin_bit_cast(bf16x8, b), c, 0, 0, 0);
}

// ---------------------------------------------------------------------------
// prep: wl_s[f][h] = sum_nh W_l[f][h*128+nh]*aw[nh];  wr_s likewise with aw[128+]
__global__ __launch_bounds__(256) void prep_kernel(
    const float* __restrict__ Wl, const float* __restrict__ Wr,
    const float* __restrict__ aw, float* __restrict__ wls, float* __restrict__ wrs) {
    int t = blockIdx.x * 256 + threadIdx.x;   // 0..2047
    int which = t >> 10;                       // 0 -> wl, 1 -> wr
    int f = (t & 1023) >> 2;
    int h = t & 3;
    const float* W = which ? Wr : Wl;
    const float* a = aw + which * NH_;
    const float* wrow = W + (size_t)f * GC_ + h * NH_;
    float s = 0.f;
    for (int k = 0; k < NH_; ++k) s += wrow[k] * a[k];
    (which ? wrs : wls)[f * H_ + h] = s;
}

// ---------------------------------------------------------------------------
// prep_bt: split Wr into bf16 hi/lo in TRANSPOSED layout bt[col][k]
__global__ __launch_bounds__(256) void prep_bt(
    const float* __restrict__ Wr, unsigned short* __restrict__ bth,
    unsigned short* __restrict__ btl) {
    int t = blockIdx.x * 256 + threadIdx.x;   // 0..16383
    int col = t >> 5, k0 = (t & 31) * 8;
    union { unsigned short us[8]; uint4 v; } ph, pl;
#pragma unroll
    for (int e = 0; e < 8; ++e) {
        float v = Wr[(size_t)(k0 + e) * GC_ + col];
        unsigned short hi = f2bf(v);
        ph.us[e] = hi;
        pl.us[e] = f2bf(v - bf2f(hi));
    }
    *(uint4*)&bth[col * F_ + k0] = ph.v;
    *(uint4*)&btl[col * F_ + k0] = pl.v;
}

// ---------------------------------------------------------------------------
// scores: one thread per row r = n*512 + sp of h.  sl/sr layout: [sp][n][h]
__global__ __launch_bounds__(256) void score_kernel(
    const float* __restrict__ hm, const float* __restrict__ wls,
    const float* __restrict__ wrs, float* __restrict__ sl, float* __restrict__ sr) {
    int r = blockIdx.x * 256 + threadIdx.x;    // 0..65535
    const float4* hr  = (const float4*)(hm + (size_t)r * F_);
    const float4* wl4 = (const float4*)wls;    // [f] -> 4 heads
    const float4* wr4 = (const float4*)wrs;
    float4 al = {0.f,0.f,0.f,0.f}, ar = {0.f,0.f,0.f,0.f};
    for (int f0 = 0; f0 < F_; f0 += 4) {
        float4 hv = hr[f0 >> 2];
        float hx[4] = {hv.x, hv.y, hv.z, hv.w};
#pragma unroll
        for (int u = 0; u < 4; ++u) {
            float4 wl = wl4[f0 + u], wr = wr4[f0 + u];
            al.x += hx[u] * wl.x; al.y += hx[u] * wl.y;
            al.z += hx[u] * wl.z; al.w += hx[u] * wl.w;
            ar.x += hx[u] * wr.x; ar.y += hx[u] * wr.y;
            ar.z += hx[u] * wr.z; ar.w += hx[u] * wr.w;
        }
    }
    int n = r >> 9, sp = r & 511;
    ((float4*)sl)[sp * N_ + n] = al;
    ((float4*)sr)[sp * N_ + n] = ar;
}

// ---------------------------------------------------------------------------
// g_r GEMM via split-bf16 MFMA: (65536 x 256) @ (256 x 512), out bf16 [sp][n][col].
__global__ __launch_bounds__(512) void gemm_mfma(
    const float* __restrict__ hm, const unsigned short* __restrict__ bth,
    const unsigned short* __restrict__ btl, unsigned short* __restrict__ g) {
    constexpr int PA = 72;
    __shared__ unsigned short Ahi[128 * PA];
    __shared__ unsigned short Alo[128 * PA];

    int rb = blockIdx.x;
    int t = threadIdx.x;
    int w = t >> 6, l = t & 63;
    int colw = w * 64;
    int ls = l & 15, kg = l >> 4;

    f32x4 acc[8][4];
#pragma unroll
    for (int m = 0; m < 8; ++m)
#pragma unroll
        for (int n = 0; n < 4; ++n) acc[m][n] = (f32x4){0.f, 0.f, 0.f, 0.f};

    const float* abase = hm + (size_t)rb * 128 * F_;

    for (int step = 0; step < 4; ++step) {
        int k0s = step * 64;
        if (step) __syncthreads();
#pragma unroll
        for (int u = 0; u < 2; ++u) {
            int gi = t + u * 512;
            int row = gi >> 3, kc = (gi & 7) * 8;
            const float* ap = abase + (size_t)row * F_ + k0s + kc;
            float4 a0 = *(const float4*)ap;
            float4 a1 = *(const float4*)(ap + 4);
            float av[8] = {a0.x, a0.y, a0.z, a0.w, a1.x, a1.y, a1.z, a1.w};
            union { unsigned short us[8]; uint4 v; } ph, pl;
#pragma unroll
            for (int e = 0; e < 8; ++e) {
                unsigned short hi = f2bf(av[e]);
                ph.us[e] = hi;
                pl.us[e] = f2bf(av[e] - bf2f(hi));
            }
            *(uint4*)&Ahi[row * PA + kc] = ph.v;
            *(uint4*)&Alo[row * PA + kc] = pl.v;
        }
        __syncthreads();

#pragma unroll
        for (int half = 0; half < 2; ++half) {
            int kglob = k0s + half * 32 + kg * 8;
            int kloc  = half * 32 + kg * 8;
            uint4 fbh[4], fbl[4];
#pragma unroll
            for (int n = 0; n < 4; ++n) {
                int c = colw + n * 16 + ls;
                fbh[n] = *(const uint4*)&bth[(size_t)c * F_ + kglob];
                fbl[n] = *(const uint4*)&btl[(size_t)c * F_ + kglob];
            }
#pragma unroll
            for (int m = 0; m < 8; ++m) {
                int row = m * 16 + ls;
                uint4 fah = *(const uint4*)&Ahi[row * PA + kloc];
                uint4 fal = *(const uint4*)&Alo[row * PA + kloc];
#pragma unroll
                for (int n = 0; n < 4; ++n) {
                    acc[m][n] = mfma16(fbh[n], fah, acc[m][n]);
                    acc[m][n] = mfma16(fbl[n], fah, acc[m][n]);
                    acc[m][n] = mfma16(fbh[n], fal, acc[m][n]);
                }
            }
        }
    }

    int n_out = rb >> 2, spb = (rb & 3) * 128;
#pragma unroll
    for (int m = 0; m < 8; ++m) {
        int sp = spb + m * 16 + ls;
        unsigned short* gr = g + (size_t)sp * 65536 + (size_t)n_out * GC_ + colw + kg * 4;
#pragma unroll
        for (int n = 0; n < 4; ++n) {
            union { unsigned short us[4]; uint2 v; } pk;
#pragma unroll
            for (int q = 0; q < 4; ++q) pk.us[q] = f2bf(acc[m][n][q]);
            *(uint2*)(gr + n * 16) = pk.v;
        }
    }
}

// ---------------------------------------------------------------------------
// Fused softmax + PV, i-split: 2 blocks per sp, each owns 64 rows (all heads,
// all 128 f).  LDS ~75 KB -> 2 blocks/CU.  8 waves; wave tile 32 i x 32 f.
__global__ __launch_bounds__(512) void smpv_kernel(
    const float* __restrict__ sl_g, const float* __restrict__ sr_g,
    const unsigned short* __restrict__ g,
    float* __restrict__ a_out, float* __restrict__ out) {
    constexpr int PH = 136;
    __shared__ unsigned short ahi[64 * PH];
    __shared__ unsigned short alo[64 * PH];
    __shared__ unsigned short ghT[128 * PH];
    __shared__ float4 sl4[N_], sr4[64];
    __shared__ float mrow[H_ * 64], invs[H_ * 64], psum[2 * H_ * 64];
    __shared__ float mx1[H_], mx2[H_];
    __shared__ int   id1[H_];

    int bid = blockIdx.x;
    int sp = bid >> 1;
    int ibase = (bid & 1) * 64;
    int t = threadIdx.x;
    int w = t >> 6, l = t & 63;
    int wi = w & 1, wf = w >> 1;
    int i0w = wi * 32, f0w = wf * 32;   // local row tile, f tile
    int ls = l & 15, kg = l >> 4;

    if (t < 128)       sl4[t]       = ((const float4*)sl_g)[sp * N_ + t];
    else if (t < 192)  sr4[t - 128] = ((const float4*)sr_g)[sp * N_ + ibase + (t - 128)];
    __syncthreads();

    if (t < H_) {
        float m1 = -1e30f; int i1 = 0;
        for (int j = 0; j < N_; ++j) {
            float v = ((const float*)&sl4[j])[t];
            if (v > m1) { m1 = v; i1 = j; }
        }
        float m2 = -1e30f;
        for (int j = 0; j < N_; ++j)
            if (j != i1) m2 = fmaxf(m2, ((const float*)&sl4[j])[t]);
        mx1[t] = m1; mx2[t] = m2; id1[t] = i1;
    }
    __syncthreads();

    {   // pass 1: per-(i,h) inv-sum; j split across 2 thread groups
        int i = t & 63, h = (t >> 6) & 3, jh = t >> 8;
        int gi = ibase + i;
        float sri = ((const float*)&sr4[i])[h];
        float m = lrelu(sri + ((id1[h] == gi) ? mx2[h] : mx1[h]));
        float sum = 0.f;
        int j0 = jh * 64;
        for (int j = j0; j < j0 + 64; ++j) {
            float e = lrelu(sri + ((const float*)&sl4[j])[h]);
            float p = __expf(e - m);
            if (j != gi) sum += p;
        }
        psum[jh * 256 + h * 64 + i] = sum;
        if (jh == 0) mrow[h * 64 + i] = m;
    }
    __syncthreads();
    if (t < 256) {
        int i = t & 63, h = t >> 6;
        invs[h * 64 + i] = 1.f / (psum[h * 64 + i] + psum[256 + h * 64 + i]);
    }
    __syncthreads();

    const unsigned short* g_base = g + (size_t)sp * 65536;
    float4* a_base = (float4*)(a_out + (size_t)sp * 65536);

    f32x4 acc[2][2];
#pragma unroll
    for (int m = 0; m < 2; ++m)
#pragma unroll
        for (int n = 0; n < 2; ++n) acc[m][n] = (f32x4){0.f, 0.f, 0.f, 0.f};

    int ai  = t >> 3;                  // local row 0..63
    int aj0 = (t & 7) * 16;            // 16 j per thread
    int gai = ibase + ai;

    for (int h = 0; h < H_; ++h) {
        if (h) __syncthreads();

        // ---- a-tile compute + LDS deposit (+ a_out write on h==0) ----
        if (h == 0) {
            float4 srv = sr4[ai];
            float4 m4 = {mrow[ai], mrow[64 + ai], mrow[128 + ai], mrow[192 + ai]};
            float4 s4 = {invs[ai], invs[64 + ai], invs[128 + ai], invs[192 + ai]};
#pragma unroll
            for (int u = 0; u < 2; ++u) {
                union { unsigned short us[8]; uint4 v; } ph_, pl_;
#pragma unroll
                for (int e = 0; e < 8; ++e) {
                    int j = aj0 + u * 8 + e;
                    float4 slv = sl4[j];
                    float4 p;
                    p.x = __expf(lrelu(srv.x + slv.x) - m4.x) * s4.x;
                    p.y = __expf(lrelu(srv.y + slv.y) - m4.y) * s4.y;
                    p.z = __expf(lrelu(srv.z + slv.z) - m4.z) * s4.z;
                    p.w = __expf(lrelu(srv.w + slv.w) - m4.w) * s4.w;
                    if (j == gai) { p.x = 0.f; p.y = 0.f; p.z = 0.f; p.w = 0.f; }
                    a_base[gai * N_ + j] = p;
                    unsigned short hi = f2bf(p.x);
                    ph_.us[e] = hi;
                    pl_.us[e] = f2bf(p.x - bf2f(hi));
                }
                *(uint4*)&ahi[ai * PH + aj0 + u * 8] = ph_.v;
                *(uint4*)&alo[ai * PH + aj0 + u * 8] = pl_.v;
            }
        } else {
            float sri = ((const float*)&sr4[ai])[h];
            float m = mrow[h * 64 + ai], s = invs[h * 64 + ai];
#pragma unroll
            for (int u = 0; u < 2; ++u) {
                union { unsigned short us[8]; uint4 v; } ph_, pl_;
#pragma unroll
                for (int e = 0; e < 8; ++e) {
                    int j = aj0 + u * 8 + e;
                    float p = (j == gai) ? 0.f
                            : __expf(lrelu(sri + ((const float*)&sl4[j])[h]) - m) * s;
                    unsigned short hi = f2bf(p);
                    ph_.us[e] = hi;
                    pl_.us[e] = f2bf(p - bf2f(hi));
                }
                *(uint4*)&ahi[ai * PH + aj0 + u * 8] = ph_.v;
                *(uint4*)&alo[ai * PH + aj0 + u * 8] = pl_.v;
            }
        }

        {   // ---- stage G^T head h: 8j x 4f micro-transpose + XOR swizzle ----
            int fq = t & 31;
            int jq = t >> 5;          // 0..15
            int f0 = fq * 4, j0 = jq * 8;
            const unsigned short* gp = g_base + h * NH_ + f0;
            unsigned short tr[8][4];
#pragma unroll
            for (int jr = 0; jr < 8; ++jr) {
                uint2 v = *(const uint2*)(gp + (size_t)(j0 + jr) * GC_);
                const unsigned short* pv = (const unsigned short*)&v;
                tr[jr][0] = pv[0]; tr[jr][1] = pv[1]; tr[jr][2] = pv[2]; tr[jr][3] = pv[3];
            }
            int jbase = j0 ^ ((((unsigned)f0 >> 3) & 3) << 3);
#pragma unroll
            for (int fz = 0; fz < 4; ++fz) {
                union { unsigned short us[8]; uint4 v; } pk;
#pragma unroll
                for (int jr = 0; jr < 8; ++jr) pk.us[jr] = tr[jr][fz];
                *(uint4*)&ghT[(f0 + fz) * PH + jbase] = pk.v;
            }
        }
        __syncthreads();

        // ---- MFMA: K = 128 over j ----
#pragma unroll
        for (int k0 = 0; k0 < 128; k0 += 32) {
            int koff = k0 + 8 * kg;
            uint4 fah[2], fal[2], fbv[2];
#pragma unroll
            for (int m = 0; m < 2; ++m) {
                int row = i0w + m * 16 + ls;
                fah[m] = *(const uint4*)&ahi[row * PH + koff];
                fal[m] = *(const uint4*)&alo[row * PH + koff];
            }
#pragma unroll
            for (int n = 0; n < 2; ++n) {
                int f = f0w + n * 16 + ls;
                int jc = koff ^ (((f >> 3) & 3) << 3);
                fbv[n] = *(const uint4*)&ghT[f * PH + jc];
            }
#pragma unroll
            for (int m = 0; m < 2; ++m)
#pragma unroll
                for (int n = 0; n < 2; ++n) {
                    acc[m][n] = mfma16(fah[m], fbv[n], acc[m][n]);
                    acc[m][n] = mfma16(fal[m], fbv[n], acc[m][n]);
                }
        }
    }

    // ---- epilogue ----
    int g4 = kg * 4;
    int c  = ls;
#pragma unroll
    for (int m = 0; m < 2; ++m) {
        int nodeb = ibase + i0w + m * 16 + g4;
#pragma unroll
        for (int n = 0; n < 2; ++n) {
            int f = f0w + n * 16 + c;
#pragma unroll
            for (int q = 0; q < 4; ++q)
                out[(size_t)(nodeb + q) * 65536 + (size_t)sp * NH_ + f] = acc[m][n][q] * 0.25f;
        }
    }
}

// ---------------------------------------------------------------------------
extern "C" void kernel_launch(void* const* d_in, const int* in_sizes, int n_in,
                              void* d_out, int out_size, void* d_ws, size_t ws_size,
                              hipStream_t stream) {
    const float* hm = (const float*)d_in[0];
    const float* Wl = (const float*)d_in[1];
    const float* Wr = (const float*)d_in[2];
    const float* aw = (const float*)d_in[3];

    float* out   = (float*)d_out;
    float* a_out = out + OUT_ELEMS;

    char* ws = (char*)d_ws;
    unsigned short* g = (unsigned short*)ws;              // 64 MiB bf16
    float* sl  = (float*)(ws + (size_t)67108864);
    float* sr  = sl + SP_ * N_ * H_;
    float* wls = sr + SP_ * N_ * H_;
    float* wrs = wls + F_ * H_;
    unsigned short* bth = (unsigned short*)(ws + (size_t)67108864 + 2113536);
    unsigned short* btl = bth + GC_ * F_;                 // 512*256 each

    prep_kernel   <<<8,           256, 0, stream>>>(Wl, Wr, aw, wls, wrs);
    prep_bt       <<<64,          256, 0, stream>>>(Wr, bth, btl);
    score_kernel  <<<ROWS_ / 256, 256, 0, stream>>>(hm, wls, wrs, sl, sr);
    gemm_mfma     <<<512,         512, 0, stream>>>(hm, bth, btl, g);
    smpv_kernel   <<<SP_ * 2,     512, 0, stream>>>(sl, sr, g, a_out, out);
}

// Round 6
// 193.881 us; speedup vs baseline: 2.9060x; 1.0131x over previous
//
#include <hip/hip_runtime.h>
#include <hip/hip_bf16.h>

#define DI __device__ __forceinline__

namespace {
constexpr int N_ = 128, S_ = 32, P_ = 16, F_ = 256, H_ = 4, NH_ = 128;
constexpr int SP_ = S_ * P_;          // 512
constexpr int ROWS_ = N_ * SP_;       // 65536
constexpr int GC_ = H_ * NH_;         // 512
constexpr float SLOPE_ = 0.2f;
constexpr int OUT_ELEMS = N_ * SP_ * NH_;    // 8,388,608
}

DI float lrelu(float x) { return x >= 0.f ? x : SLOPE_ * x; }

DI unsigned short f2h(float x) {
    _Float16 h = (_Float16)x;
    return __builtin_bit_cast(unsigned short, h);
}
DI float h2f(unsigned short b) {
    return (float)__builtin_bit_cast(_Float16, b);
}

typedef _Float16 f16x8 __attribute__((ext_vector_type(8)));
typedef float    f32x4 __attribute__((ext_vector_type(4)));

DI f32x4 mfma16h(uint4 a, uint4 b, f32x4 c) {
    return __builtin_amdgcn_mfma_f32_16x16x32_f16(
        __builtin_bit_cast(f16x8, a), __builtin_bit_cast(f16x8, b), c, 0, 0, 0);
}

// ---------------------------------------------------------------------------
// prep: wl_s[f][h] = sum_nh W_l[f][h*128+nh]*aw[nh];  wr_s likewise with aw[128+]
__global__ __launch_bounds__(256) void prep_kernel(
    const float* __restrict__ Wl, const float* __restrict__ Wr,
    const float* __restrict__ aw, float* __restrict__ wls, float* __restrict__ wrs) {
    int t = blockIdx.x * 256 + threadIdx.x;   // 0..2047
    int which = t >> 10;                       // 0 -> wl, 1 -> wr
    int f = (t & 1023) >> 2;
    int h = t & 3;
    const float* W = which ? Wr : Wl;
    const float* a = aw + which * NH_;
    const float* wrow = W + (size_t)f * GC_ + h * NH_;
    float s = 0.f;
    for (int k = 0; k < NH_; ++k) s += wrow[k] * a[k];
    (which ? wrs : wls)[f * H_ + h] = s;
}

// ---------------------------------------------------------------------------
// prep_bt: split Wr*256 into f16 hi/lo in TRANSPOSED layout bt[col][k].
// x256 (exact power of 2, undone in gemm epilogue) keeps lo in f16 normal range.
__global__ __launch_bounds__(256) void prep_bt(
    const float* __restrict__ Wr, unsigned short* __restrict__ bth,
    unsigned short* __restrict__ btl) {
    int t = blockIdx.x * 256 + threadIdx.x;   // 0..16383
    int col = t >> 5, k0 = (t & 31) * 8;
    union { unsigned short us[8]; uint4 v; } ph, pl;
#pragma unroll
    for (int e = 0; e < 8; ++e) {
        float v = Wr[(size_t)(k0 + e) * GC_ + col] * 256.0f;
        unsigned short hi = f2h(v);
        ph.us[e] = hi;
        pl.us[e] = f2h(v - h2f(hi));
    }
    *(uint4*)&bth[col * F_ + k0] = ph.v;
    *(uint4*)&btl[col * F_ + k0] = pl.v;
}

// ---------------------------------------------------------------------------
// scores: one thread per row r = n*512 + sp of h.  sl/sr layout: [sp][n][h]
__global__ __launch_bounds__(256) void score_kernel(
    const float* __restrict__ hm, const float* __restrict__ wls,
    const float* __restrict__ wrs, float* __restrict__ sl, float* __restrict__ sr) {
    int r = blockIdx.x * 256 + threadIdx.x;    // 0..65535
    const float4* hr  = (const float4*)(hm + (size_t)r * F_);
    const float4* wl4 = (const float4*)wls;    // [f] -> 4 heads
    const float4* wr4 = (const float4*)wrs;
    float4 al = {0.f,0.f,0.f,0.f}, ar = {0.f,0.f,0.f,0.f};
    for (int f0 = 0; f0 < F_; f0 += 4) {
        float4 hv = hr[f0 >> 2];
        float hx[4] = {hv.x, hv.y, hv.z, hv.w};
#pragma unroll
        for (int u = 0; u < 4; ++u) {
            float4 wl = wl4[f0 + u], wr = wr4[f0 + u];
            al.x += hx[u] * wl.x; al.y += hx[u] * wl.y;
            al.z += hx[u] * wl.z; al.w += hx[u] * wl.w;
            ar.x += hx[u] * wr.x; ar.y += hx[u] * wr.y;
            ar.z += hx[u] * wr.z; ar.w += hx[u] * wr.w;
        }
    }
    int n = r >> 9, sp = r & 511;
    ((float4*)sl)[sp * N_ + n] = al;
    ((float4*)sr)[sp * N_ + n] = ar;
}

// ---------------------------------------------------------------------------
// g_r GEMM via split-f16 MFMA: (65536 x 256) @ (256 x 512), out f16 [sp][n][col].
__global__ __launch_bounds__(512) void gemm_mfma(
    const float* __restrict__ hm, const unsigned short* __restrict__ bth,
    const unsigned short* __restrict__ btl, unsigned short* __restrict__ g) {
    constexpr int PA = 72;
    __shared__ unsigned short Ahi[128 * PA];
    __shared__ unsigned short Alo[128 * PA];

    int rb = blockIdx.x;
    int t = threadIdx.x;
    int w = t >> 6, l = t & 63;
    int colw = w * 64;
    int ls = l & 15, kg = l >> 4;

    f32x4 acc[8][4];
#pragma unroll
    for (int m = 0; m < 8; ++m)
#pragma unroll
        for (int n = 0; n < 4; ++n) acc[m][n] = (f32x4){0.f, 0.f, 0.f, 0.f};

    const float* abase = hm + (size_t)rb * 128 * F_;

    for (int step = 0; step < 4; ++step) {
        int k0s = step * 64;
        if (step) __syncthreads();
#pragma unroll
        for (int u = 0; u < 2; ++u) {
            int gi = t + u * 512;
            int row = gi >> 3, kc = (gi & 7) * 8;
            const float* ap = abase + (size_t)row * F_ + k0s + kc;
            float4 a0 = *(const float4*)ap;
            float4 a1 = *(const float4*)(ap + 4);
            float av[8] = {a0.x, a0.y, a0.z, a0.w, a1.x, a1.y, a1.z, a1.w};
            union { unsigned short us[8]; uint4 v; } ph, pl;
#pragma unroll
            for (int e = 0; e < 8; ++e) {
                unsigned short hi = f2h(av[e]);
                ph.us[e] = hi;
                pl.us[e] = f2h(av[e] - h2f(hi));
            }
            *(uint4*)&Ahi[row * PA + kc] = ph.v;
            *(uint4*)&Alo[row * PA + kc] = pl.v;
        }
        __syncthreads();

#pragma unroll
        for (int half = 0; half < 2; ++half) {
            int kglob = k0s + half * 32 + kg * 8;
            int kloc  = half * 32 + kg * 8;
            uint4 fbh[4], fbl[4];
#pragma unroll
            for (int n = 0; n < 4; ++n) {
                int c = colw + n * 16 + ls;
                fbh[n] = *(const uint4*)&bth[(size_t)c * F_ + kglob];
                fbl[n] = *(const uint4*)&btl[(size_t)c * F_ + kglob];
            }
#pragma unroll
            for (int m = 0; m < 8; ++m) {
                int row = m * 16 + ls;
                uint4 fah = *(const uint4*)&Ahi[row * PA + kloc];
                uint4 fal = *(const uint4*)&Alo[row * PA + kloc];
#pragma unroll
                for (int n = 0; n < 4; ++n) {
                    acc[m][n] = mfma16h(fbh[n], fah, acc[m][n]);   // hi*hi
                    acc[m][n] = mfma16h(fbl[n], fah, acc[m][n]);   // loB*hiA
                    acc[m][n] = mfma16h(fbh[n], fal, acc[m][n]);   // hiB*loA
                }
            }
        }
    }

    // epilogue: undo x256 scale, f16 pack, D[c][r] -> 4 contiguous cols per lane
    int n_out = rb >> 2, spb = (rb & 3) * 128;
#pragma unroll
    for (int m = 0; m < 8; ++m) {
        int sp = spb + m * 16 + ls;
        unsigned short* gr = g + (size_t)sp * 65536 + (size_t)n_out * GC_ + colw + kg * 4;
#pragma unroll
        for (int n = 0; n < 4; ++n) {
            union { unsigned short us[4]; uint2 v; } pk;
#pragma unroll
            for (int q = 0; q < 4; ++q) pk.us[q] = f2h(acc[m][n][q] * 0.00390625f);
            *(uint2*)(gr + n * 16) = pk.v;
        }
    }
}

// ---------------------------------------------------------------------------
// Fused softmax + PV, f16 single-precision-split: one block per sp (512 thr).
// LDS ~76 KB -> 2 blocks/CU, 512 blocks all co-resident.
__global__ __launch_bounds__(512) void smpv_kernel(
    const float* __restrict__ sl_g, const float* __restrict__ sr_g,
    const unsigned short* __restrict__ g,
    float* __restrict__ a_out, float* __restrict__ out) {
    constexpr int PH = 136;
    __shared__ unsigned short ah[128 * PH];
    __shared__ unsigned short ghT[128 * PH];
    __shared__ float4 sl4[N_], sr4[N_], mrow[N_], invs[N_];
    __shared__ float mx1[H_], mx2[H_];
    __shared__ int   id1[H_];

    int sp = blockIdx.x;
    int t = threadIdx.x;
    int w = t >> 6, l = t & 63;
    int i0  = (w & 3) * 32;              // wave tile: 32 i x 64 f
    int f0w = (w >> 2) * 64;
    int ls = l & 15, kg = l >> 4;

    if (t < 128)       sl4[t]       = ((const float4*)sl_g)[sp * N_ + t];
    else if (t < 256)  sr4[t - 128] = ((const float4*)sr_g)[sp * N_ + (t - 128)];
    __syncthreads();

    if (t < H_) {
        float m1 = -1e30f; int i1 = 0;
        for (int j = 0; j < N_; ++j) {
            float v = ((const float*)&sl4[j])[t];
            if (v > m1) { m1 = v; i1 = j; }
        }
        float m2 = -1e30f;
        for (int j = 0; j < N_; ++j)
            if (j != i1) m2 = fmaxf(m2, ((const float*)&sl4[j])[t]);
        mx1[t] = m1; mx2[t] = m2; id1[t] = i1;
    }
    __syncthreads();

    {   // pass 1: per-(i,h) max (monotonicity) and inv-sum
        int i = t & 127, h = t >> 7;
        float sri = ((const float*)&sr4[i])[h];
        float m = lrelu(sri + ((id1[h] == i) ? mx2[h] : mx1[h]));
        float sum = 0.f;
        for (int j = 0; j < N_; ++j) {
            float e = lrelu(sri + ((const float*)&sl4[j])[h]);
            float p = __expf(e - m);
            if (j != i) sum += p;
        }
        ((float*)&mrow[i])[h] = m;
        ((float*)&invs[i])[h] = 1.f / sum;
    }
    __syncthreads();

    const unsigned short* g_base = g + (size_t)sp * 65536;
    float4* a_base = (float4*)(a_out + (size_t)sp * 65536);

    f32x4 acc[2][4];
#pragma unroll
    for (int m = 0; m < 2; ++m)
#pragma unroll
        for (int n = 0; n < 4; ++n) acc[m][n] = (f32x4){0.f, 0.f, 0.f, 0.f};

    for (int h = 0; h < H_; ++h) {
        if (h) __syncthreads();

        {   // a-tile compute + f16 LDS deposit (+ coalesced a_out write on h==0)
            int i = t >> 2, j0 = (t & 3) * 32;
            float4 srv = sr4[i], m4 = mrow[i], s4 = invs[i];
            if (h == 0) {
#pragma unroll
                for (int u = 0; u < 4; ++u) {
                    union { unsigned short us[8]; uint4 v; } pk;
#pragma unroll
                    for (int e = 0; e < 8; ++e) {
                        int j = j0 + u * 8 + e;
                        float4 slv = sl4[j];
                        float4 p;
                        p.x = __expf(lrelu(srv.x + slv.x) - m4.x) * s4.x;
                        p.y = __expf(lrelu(srv.y + slv.y) - m4.y) * s4.y;
                        p.z = __expf(lrelu(srv.z + slv.z) - m4.z) * s4.z;
                        p.w = __expf(lrelu(srv.w + slv.w) - m4.w) * s4.w;
                        if (j == i) { p.x = 0.f; p.y = 0.f; p.z = 0.f; p.w = 0.f; }
                        a_base[i * N_ + j] = p;
                        pk.us[e] = f2h(p.x);
                    }
                    *(uint4*)&ah[i * PH + j0 + u * 8] = pk.v;
                }
            } else {
                float sri = ((const float*)&srv)[h];
                float m = ((const float*)&m4)[h], s = ((const float*)&s4)[h];
#pragma unroll
                for (int u = 0; u < 4; ++u) {
                    union { unsigned short us[8]; uint4 v; } pk;
#pragma unroll
                    for (int e = 0; e < 8; ++e) {
                        int j = j0 + u * 8 + e;
                        float p = (j == i) ? 0.f
                                : __expf(lrelu(sri + ((const float*)&sl4[j])[h]) - m) * s;
                        pk.us[e] = f2h(p);
                    }
                    *(uint4*)&ah[i * PH + j0 + u * 8] = pk.v;
                }
            }
        }
        {   // stage G^T head h: 8j x 4f micro-transpose, fq-XOR swizzle (bank-uniform)
            int fq = t & 31;            // f0 = fq*4  (coalesced global reads)
            int jq = t >> 5;            // j0 = jq*8
            int f0 = fq * 4, j0 = jq * 8;
            const unsigned short* gp = g_base + h * NH_ + f0;
            unsigned short tr[8][4];
#pragma unroll
            for (int jr = 0; jr < 8; ++jr) {
                uint2 v = *(const uint2*)(gp + (size_t)(j0 + jr) * GC_);
                const unsigned short* pv = (const unsigned short*)&v;
                tr[jr][0] = pv[0]; tr[jr][1] = pv[1]; tr[jr][2] = pv[2]; tr[jr][3] = pv[3];
            }
            int jbase = j0 ^ ((fq & 7) << 3);     // s(f) = (f>>2)&7
#pragma unroll
            for (int fz = 0; fz < 4; ++fz) {
                union { unsigned short us[8]; uint4 v; } pk;
#pragma unroll
                for (int jr = 0; jr < 8; ++jr) pk.us[jr] = tr[jr][fz];
                *(uint4*)&ghT[(f0 + fz) * PH + jbase] = pk.v;
            }
        }
        __syncthreads();

        // MFMA: K = 128 over j (single f16 product per operand pair)
#pragma unroll
        for (int k0 = 0; k0 < 128; k0 += 32) {
            int koff = k0 + 8 * kg;
            uint4 fah[2], fbv[4];
#pragma unroll
            for (int m = 0; m < 2; ++m) {
                int row = i0 + m * 16 + ls;
                fah[m] = *(const uint4*)&ah[row * PH + koff];
            }
#pragma unroll
            for (int n = 0; n < 4; ++n) {
                int f = f0w + n * 16 + ls;
                int jc = koff ^ (((f >> 2) & 7) << 3);
                fbv[n] = *(const uint4*)&ghT[f * PH + jc];
            }
#pragma unroll
            for (int m = 0; m < 2; ++m)
#pragma unroll
                for (int n = 0; n < 4; ++n)
                    acc[m][n] = mfma16h(fah[m], fbv[n], acc[m][n]);
        }
    }

    int g4 = kg * 4;
    int c  = ls;
#pragma unroll
    for (int m = 0; m < 2; ++m) {
        int ibase = i0 + m * 16 + g4;
#pragma unroll
        for (int n = 0; n < 4; ++n) {
            int f = f0w + n * 16 + c;
#pragma unroll
            for (int q = 0; q < 4; ++q)
                out[(size_t)(ibase + q) * 65536 + (size_t)sp * NH_ + f] = acc[m][n][q] * 0.25f;
        }
    }
}

// ---------------------------------------------------------------------------
extern "C" void kernel_launch(void* const* d_in, const int* in_sizes, int n_in,
                              void* d_out, int out_size, void* d_ws, size_t ws_size,
                              hipStream_t stream) {
    const float* hm = (const float*)d_in[0];
    const float* Wl = (const float*)d_in[1];
    const float* Wr = (const float*)d_in[2];
    const float* aw = (const float*)d_in[3];

    float* out   = (float*)d_out;
    float* a_out = out + OUT_ELEMS;

    char* ws = (char*)d_ws;
    unsigned short* g = (unsigned short*)ws;              // 64 MiB f16
    float* sl  = (float*)(ws + (size_t)67108864);
    float* sr  = sl + SP_ * N_ * H_;
    float* wls = sr + SP_ * N_ * H_;
    float* wrs = wls + F_ * H_;
    unsigned short* bth = (unsigned short*)(ws + (size_t)67108864 + 2113536);
    unsigned short* btl = bth + GC_ * F_;                 // 512*256 each

    prep_kernel   <<<8,           256, 0, stream>>>(Wl, Wr, aw, wls, wrs);
    prep_bt       <<<64,          256, 0, stream>>>(Wr, bth, btl);
    score_kernel  <<<ROWS_ / 256, 256, 0, stream>>>(hm, wls, wrs, sl, sr);
    gemm_mfma     <<<512,         512, 0, stream>>>(hm, bth, btl, g);
    smpv_kernel   <<<SP_,         512, 0, stream>>>(sl, sr, g, a_out, out);
}